// Round 1
// 237.359 us; speedup vs baseline: 1.0838x; 1.0838x over previous
//
#include <hip/hip_runtime.h>
#include <hip/hip_bf16.h>

#define BB 32
#define TT 64
#define NN 512
#define HH 64

using u16 = unsigned short;
using u32 = unsigned int;
typedef _Float16 f16x8 __attribute__((ext_vector_type(8)));
typedef _Float16 f16x2h __attribute__((ext_vector_type(2)));
typedef __fp16 fp16x2 __attribute__((ext_vector_type(2)));
typedef __attribute__((ext_vector_type(4))) float f32x4;

__device__ __forceinline__ u16 f2h_bits(float f) {
  _Float16 h = (_Float16)f;  // v_cvt_f16_f32, RNE, 1 instr
  u16 u; __builtin_memcpy(&u, &h, 2); return u;
}
__device__ __forceinline__ u32 pk2h(float a, float b) {  // v_cvt_pkrtz, 1 instr
  fp16x2 h = __builtin_amdgcn_cvt_pkrtz(a, b);
  u32 u; __builtin_memcpy(&u, &h, 4); return u;
}
__device__ __forceinline__ f16x2h pkh(float a, float b) {  // pkrtz -> _Float16 pair
  fp16x2 h = __builtin_amdgcn_cvt_pkrtz(a, b);
  f16x2h r; __builtin_memcpy(&r, &h, 4); return r;
}

// async global->LDS, 16B per lane; lds base wave-uniform, lane i lands at
// ldsbase + i*16; GLOBAL address is per-lane (must include lane term).
__device__ __forceinline__ void gld_lds16(const void* g, void* l) {
  __builtin_amdgcn_global_load_lds(
      (const __attribute__((address_space(1))) u32*)g,
      (__attribute__((address_space(3))) u32*)l, 16, 0, 0);
}

// ---------------------------------------------------------------------------
// conversion kernels (run once per call) — all outputs fp16
// ---------------------------------------------------------------------------
__global__ __launch_bounds__(256) void kcvt_adj(const float* __restrict__ a,
                                                u16* __restrict__ o) {
  const int i = blockIdx.x * 256 + threadIdx.x;  // 262144 total
  o[i] = f2h_bits(a[i]);
}
__global__ __launch_bounds__(256) void kcvt_x(const float* __restrict__ x,
                                              u16* __restrict__ o) {
  const int i = blockIdx.x * 256 + threadIdx.x;  // 1048576 total
  o[i] = f2h_bits(x[i]);
}
__global__ __launch_bounds__(256) void kcvt_w2t(const float* __restrict__ w2,
                                                u16* __restrict__ o) {
  const int i = blockIdx.x * 256 + threadIdx.x;  // 2048 total, o[h*32+c]
  const int h = i >> 5, c = i & 31;
  o[i] = f2h_bits(w2[c * 64 + h]);
}
// tcn_w [n][ho][hi][kk] (fp32) -> Wb [n][kk][ho][his] (f16), his = hi with its
// 16B unit XOR-swizzled by (ho&7) (involution). Coalesced read -> LDS scatter
// -> coalesced 16B write. grid (512 n), 256 threads.
__global__ __launch_bounds__(256) void kcvt_w(const float* __restrict__ tw,
                                              u16* __restrict__ o) {
  __shared__ u16 wl[3][64][64];  // [kk][ho][his], 24KB
  const int tid = threadIdx.x;
  const int n = blockIdx.x;
  const float4* pf = (const float4*)(tw + (size_t)n * 12288);
#pragma unroll
  for (int q = 0; q < 12; ++q) {
    const int fi = q * 256 + tid;
    const float4 v = pf[fi];
    const float f[4] = {v.x, v.y, v.z, v.w};
#pragma unroll
    for (int j = 0; j < 4; ++j) {
      const int e = fi * 4 + j;
      const int ho = e / 192;
      const int rem = e - ho * 192;
      const int hi = rem / 3;
      const int kk = rem - hi * 3;
      const int his = (((hi >> 3) ^ (ho & 7)) << 3) | (hi & 7);
      wl[kk][ho][his] = f2h_bits(f[j]);
    }
  }
  __syncthreads();
  const u16* src = &wl[0][0][0];
  u16* dst = o + (size_t)n * 12288;
#pragma unroll
  for (int q = 0; q < 6; ++q) {
    const int u = q * 256 + tid;  // 1536 16B units
    *(uint4*)(dst + u * 8) = *(const uint4*)(src + u * 8);
  }
}

// ---------------------------------------------------------------------------
// K0 (MFMA f16): S[bt][u] = sum_v xh[bt][v] * adjb[u][v], fp32 out.
// R7-verified gemm_bt pattern: 128x128 tile, BK=64, gld_lds w16, XOR LDS.
// grid (16 m-tiles, 4 n-tiles), 256 threads, 2x2 waves.
// ---------------------------------------------------------------------------
__global__ __launch_bounds__(256) void k0h(const u16* __restrict__ A,
                                           const u16* __restrict__ Bm,
                                           float* __restrict__ Sg) {
  __shared__ __align__(16) char smem[32768];  // As 16KB | Bs 16KB
  const int tid = threadIdx.x;
  const int w = tid >> 6, l = tid & 63;
  const int quad = l >> 4, lr = l & 15;
  const int m0 = blockIdx.x * 128, n0 = blockIdx.y * 128;
  const int wm = w >> 1, wn = w & 1;
  const int rB = w * 8 + (l >> 3);
  const int uu = l & 7;
  const u16* agp[4]; const u16* bgp[4];
#pragma unroll
  for (int c = 0; c < 4; ++c) {
    const int r = rB + c * 32;
    agp[c] = A + (size_t)(m0 + r) * 512 + ((uu ^ (r & 7)) * 8);
    bgp[c] = Bm + (size_t)(n0 + r) * 512 + ((uu ^ (r & 7)) * 8);
  }
  char* As = smem;
  char* Bs = smem + 16384;
  int arow[4], brow[4];
#pragma unroll
  for (int i = 0; i < 4; ++i) {
    arow[i] = (wm * 64 + i * 16 + lr) * 128;
    brow[i] = (wn * 64 + i * 16 + lr) * 128;
  }
  const f32x4 zz = {0.f, 0.f, 0.f, 0.f};
  f32x4 acc[4][4];
#pragma unroll
  for (int i = 0; i < 4; ++i)
#pragma unroll
    for (int j = 0; j < 4; ++j) acc[i][j] = zz;
  const int lx7 = lr & 7;
  for (int kt = 0; kt < 8; ++kt) {
#pragma unroll
    for (int c = 0; c < 4; ++c) {
      gld_lds16(agp[c] + kt * 64, As + (c * 32 + w * 8) * 128);
      gld_lds16(bgp[c] + kt * 64, Bs + (c * 32 + w * 8) * 128);
    }
    __syncthreads();
#pragma unroll
    for (int ks = 0; ks < 2; ++ks) {
      const int coff = (((ks * 4 + quad) ^ lx7)) * 16;
      f16x8 afr[4], bfr[4];
#pragma unroll
      for (int i = 0; i < 4; ++i) afr[i] = *(const f16x8*)(As + arow[i] + coff);
#pragma unroll
      for (int j = 0; j < 4; ++j) bfr[j] = *(const f16x8*)(Bs + brow[j] + coff);
#pragma unroll
      for (int i = 0; i < 4; ++i)
#pragma unroll
        for (int j = 0; j < 4; ++j)
          acc[i][j] = __builtin_amdgcn_mfma_f32_16x16x32_f16(afr[i], bfr[j], acc[i][j], 0, 0, 0);
    }
    __syncthreads();
  }
#pragma unroll
  for (int i = 0; i < 4; ++i) {
    const int m0r = m0 + wm * 64 + i * 16 + quad * 4;
#pragma unroll
    for (int j = 0; j < 4; ++j) {
      const int nn = n0 + wn * 64 + j * 16 + lr;
#pragma unroll
      for (int r = 0; r < 4; ++r)
        Sg[(size_t)(m0r + r) * 512 + nn] = acc[i][j][r];
    }
  }
}

// ---------------------------------------------------------------------------
// K2 fused (K1+K2), fp16, 1 M-tile (R13 shape, proven): C = relu(adj·G + b2),
// G panel built in-LDS per kt via small MFMAs; phi via packed f16 VALU.
// Next-kt S scalars prefetched during the MFMA phase.
// grid (tm=4, tn=Nc/128), 256 threads, 2x2 waves, 32KB LDS.
// ---------------------------------------------------------------------------
__global__ __launch_bounds__(256) void k2_fused(
    const u16* __restrict__ A, const float* __restrict__ Sg,
    const float* __restrict__ w1g, const float* __restrict__ b1g,
    const u16* __restrict__ w2t, const float* __restrict__ b2g,
    u16* __restrict__ C, int Nc, int b0) {
  __shared__ __align__(16) char smem[32768];  // As 16KB | Bs 16KB
  const int tid = threadIdx.x;
  const int w = tid >> 6, l = tid & 63;
  const int quad = l >> 4, lr = l & 15;
  const int tm = blockIdx.x, tn = blockIdx.y;
  const int m0 = tm * 128, n0 = tn * 128;
  const int wm = w >> 1, wn = w & 1;
  const int rB = w * 8 + (l >> 3);
  const int uu = l & 7;
  const u16* agp[4];
#pragma unroll
  for (int c = 0; c < 4; ++c) {
    const int r = rB + c * 32;
    agp[c] = A + (size_t)(m0 + r) * 512 + ((uu ^ (r & 7)) * 8);
  }
  char* As = smem;
  char* Bs = smem + 16384;
  const int t_loc = w & 1, vtb = (w >> 1) << 1;
  const int t = ((n0 >> 6) + t_loc) & 63;
  const int bp = n0 >> 12;
  const size_t sRow = ((size_t)((b0 + bp) * 64 + t)) << 9;
  f16x8 w1h, b1h, zero8;
#pragma unroll
  for (int j = 0; j < 8; ++j) {
    w1h[j] = (_Float16)w1g[quad * 8 + j];
    b1h[j] = (_Float16)b1g[quad * 8 + j];
    zero8[j] = (_Float16)0.f;
  }
  f16x8 wf[4];
#pragma unroll
  for (int ht = 0; ht < 4; ++ht)
    wf[ht] = *(const f16x8*)(w2t + (ht * 16 + lr) * 32 + quad * 8);
  int arow[4], brow[4];
#pragma unroll
  for (int i = 0; i < 4; ++i) {
    arow[i] = (wm * 64 + i * 16 + lr) * 128;
    brow[i] = (wn * 64 + i * 16 + lr) * 128;
  }
  const f32x4 zz = {0.f, 0.f, 0.f, 0.f};
  f32x4 acc[4][4];
#pragma unroll
  for (int i = 0; i < 4; ++i)
#pragma unroll
    for (int j = 0; j < 4; ++j) acc[i][j] = zz;
  const int lx7 = lr & 7;
  // S prefetch for kt=0
  float sv0 = Sg[sRow + (vtb + 0) * 16 + lr];
  float sv1 = Sg[sRow + (vtb + 1) * 16 + lr];
  for (int kt = 0; kt < 8; ++kt) {
#pragma unroll
    for (int c = 0; c < 4; ++c)
      gld_lds16(agp[c] + kt * 64, As + (c * 32 + w * 8) * 128);
    // build B panel: G[row=t_loc*64+h][v-chunk] via MFMA, ds_write_b64
#pragma unroll
    for (int vi = 0; vi < 2; ++vi) {
      const int vt = vtb + vi;
      const _Float16 svh = (_Float16)(vi ? sv1 : sv0);
      f16x8 svp;
#pragma unroll
      for (int j = 0; j < 8; ++j) svp[j] = svh;
      f16x8 afS = __builtin_elementwise_max(w1h * svp + b1h, zero8);
      const int qv = vt * 2 + (quad >> 1);
      const int bofs = ((qv ^ lx7) << 4) + ((quad & 1) << 3);
#pragma unroll
      for (int ht = 0; ht < 4; ++ht) {
        f32x4 p = __builtin_amdgcn_mfma_f32_16x16x32_f16(afS, wf[ht], zz, 0, 0, 0);
        uint2 st;
        st.x = pk2h(p[0], p[1]);
        st.y = pk2h(p[2], p[3]);
        const int row = t_loc * 64 + ht * 16 + lr;
        *(uint2*)(Bs + row * 128 + bofs) = st;
      }
    }
    // prefetch next kt's S scalars (overlaps MFMA phase below)
    if (kt < 7) {
      sv0 = Sg[sRow + (kt + 1) * 64 + (vtb + 0) * 16 + lr];
      sv1 = Sg[sRow + (kt + 1) * 64 + (vtb + 1) * 16 + lr];
    }
    __syncthreads();
#pragma unroll
    for (int ks = 0; ks < 2; ++ks) {
      const int coff = (((ks * 4 + quad) ^ lx7)) * 16;
      f16x8 afr[4], bfr[4];
#pragma unroll
      for (int i = 0; i < 4; ++i) afr[i] = *(const f16x8*)(As + arow[i] + coff);
#pragma unroll
      for (int j = 0; j < 4; ++j) bfr[j] = *(const f16x8*)(Bs + brow[j] + coff);
#pragma unroll
      for (int i = 0; i < 4; ++i)
#pragma unroll
        for (int j = 0; j < 4; ++j)
          acc[i][j] = __builtin_amdgcn_mfma_f32_16x16x32_f16(afr[i], bfr[j], acc[i][j], 0, 0, 0);
    }
    __syncthreads();
  }
  // epilogue: bias+relu, write with per-(t)-row XOR swizzle on 16B units
  const int nb = n0 + wn * 64;
  const int tcol = (nb >> 6) & 63;
  const int bpcol = nb >> 12;
  const int tx7 = tcol & 7;
  float bias[4];
#pragma unroll
  for (int j = 0; j < 4; ++j) bias[j] = b2g[j * 16 + lr];  // true h = j*16+lr
#pragma unroll
  for (int j = 0; j < 4; ++j) {
    const int h = j * 16 + lr;
    const int hsw = (((h >> 3) ^ tx7) << 3) | (h & 7);
    const size_t colb = (size_t)bpcol * 4096 + tcol * 64 + hsw;
#pragma unroll
    for (int i = 0; i < 4; ++i) {
      const int u0r = m0 + wm * 64 + i * 16 + quad * 4;
#pragma unroll
      for (int r = 0; r < 4; ++r) {
        const float vv = fmaxf(acc[i][j][r] + bias[j], 0.f);
        C[(size_t)(u0r + r) * Nc + colb] = f2h_bits(vv);
      }
    }
  }
}

// ---------------------------------------------------------------------------
// K3 (MFMA, fp16): grid (NN) x 4 waves. W slab (24KB, pre-swizzled) in LDS
// once per block. Wave loops bp over its private 8KB LDS slab.
// R-this: the VGPR prefetch buffer (pf[8], 32 VGPRs) + runtime-indexed
// part[8] were spilling to scratch every iteration (rocprof: 104 MB of
// writes during k3's window vs 64 KB of real output -> ~47k cyc/iter,
// all-stalled). Replaced with:
//   - async global_load_lds prefetch directly into the wave slab (issued
//     after lgkmcnt(0) drains the MFMA-phase ds_reads; the pure-register
//     FC epilogue runs between issue and the vmcnt(0), covering latency)
//   - per-iteration shfl_xor reduce + lane-0 store (part[] eliminated)
// Zero scratch; ~32 fewer live VGPRs.
// ---------------------------------------------------------------------------
__global__ __launch_bounds__(256, 2) void k3_tcn(const u16* __restrict__ H2,
                                                 const u16* __restrict__ Wb,
                                                 const float* __restrict__ tbg,
                                                 const float* __restrict__ fwg,
                                                 const float* __restrict__ fbg,
                                                 float* __restrict__ outg,
                                                 int b0, int Nc, int CBcur) {
  __shared__ __align__(16) char wlds[24576];
  __shared__ __align__(16) char hlds[4][8192];
  const int tid = threadIdx.x;
  const int n = blockIdx.x;
  const int w = tid >> 6, l = tid & 63;
  const int quad = l >> 4, lr = l & 15;
  const u16* Wp = Wb + (size_t)n * 12288;
#pragma unroll
  for (int c = 0; c < 6; ++c)
    gld_lds16(Wp + (c * 4 + w) * 512 + (size_t)l * 8, wlds + (c * 4 + w) * 1024);
  float tbv[4][4];
#pragma unroll
  for (int i = 0; i < 4; ++i)
#pragma unroll
    for (int r = 0; r < 4; ++r) tbv[i][r] = tbg[n * 64 + i * 16 + quad * 4 + r];
  f16x2h fwh[16][2];
#pragma unroll
  for (int i = 0; i < 4; ++i)
#pragma unroll
    for (int r = 0; r < 4; ++r) {
      const float* fb = fwg + (i * 16 + quad * 4 + r) * 64 + lr;
      fwh[i * 4 + r][0] = pkh(fb[0], fb[16]);
      fwh[i * 4 + r][1] = pkh(fb[32], fb[48]);
    }
  const float fcb = fbg[0];
  f16x8 bz;
#pragma unroll
  for (int jj = 0; jj < 8; ++jj) bz[jj] = (_Float16)0.f;
  char* myl = hlds[w];
  if (w < CBcur) {
    const u16* Hs0 = H2 + (size_t)n * Nc + w * 4096;
#pragma unroll
    for (int c = 0; c < 8; ++c)
      gld_lds16(Hs0 + c * 512 + (size_t)l * 8, myl + c * 1024);
  }
  asm volatile("s_waitcnt vmcnt(0)" ::: "memory");
  __syncthreads();
  const int lx7 = lr & 7;
  const f32x4 zz = {0.f, 0.f, 0.f, 0.f};
  for (int bp = w; bp < CBcur; bp += 4) {
    const bool hasNext = (bp + 4) < CBcur;
    f32x4 acc[4][4];
#pragma unroll
    for (int i = 0; i < 4; ++i)
#pragma unroll
      for (int j = 0; j < 4; ++j) acc[i][j] = zz;
#pragma unroll
    for (int ks = 0; ks < 2; ++ks)
#pragma unroll
      for (int kk = 0; kk < 3; ++kk) {
        const int usw = ((ks * 4 + quad) ^ lx7) << 4;
        f16x8 afr[4], bfr[4];
#pragma unroll
        for (int i = 0; i < 4; ++i)
          afr[i] = *(const f16x8*)(wlds + kk * 8192 + (i * 16 + lr) * 128 + usw);
#pragma unroll
        for (int j = 0; j < 4; ++j) {
          const int tau = j * 16 + lr + kk - 1;
          const int tc = min(max(tau, 0), 63);
          const int off = tc * 128 + (((ks * 4 + quad) ^ (tc & 7)) << 4);
          const f16x8 v = *(const f16x8*)(myl + off);
          bfr[j] = (tau == tc) ? v : bz;
        }
#pragma unroll
        for (int i = 0; i < 4; ++i)
#pragma unroll
          for (int j = 0; j < 4; ++j)
            acc[i][j] = __builtin_amdgcn_mfma_f32_16x16x32_f16(afr[i], bfr[j],
                                                               acc[i][j], 0, 0, 0);
      }
    // all slab ds_reads delivered -> safe to overwrite myl asynchronously
    asm volatile("s_waitcnt lgkmcnt(0)" ::: "memory");
    __builtin_amdgcn_sched_barrier(0);
    if (hasNext) {
      const u16* Hn = H2 + (size_t)n * Nc + (bp + 4) * 4096;
#pragma unroll
      for (int c = 0; c < 8; ++c)
        gld_lds16(Hn + c * 512 + (size_t)l * 8, myl + c * 1024);
    }
    // pure-register epilogue runs while the prefetch is in flight
    f16x2h pacc;
    pacc[0] = (_Float16)0.f; pacc[1] = (_Float16)0.f;
#pragma unroll
    for (int i = 0; i < 4; ++i)
#pragma unroll
      for (int r = 0; r < 4; ++r) {
        const float v0 = fmaxf(acc[i][0][r] + tbv[i][r], 0.f);
        const float v1 = fmaxf(acc[i][1][r] + tbv[i][r], 0.f);
        const float v2 = fmaxf(acc[i][2][r] + tbv[i][r], 0.f);
        const float v3 = fmaxf(acc[i][3][r] + tbv[i][r], 0.f);
        pacc = pkh(v0, v1) * fwh[i * 4 + r][0] + pacc;
        pacc = pkh(v2, v3) * fwh[i * 4 + r][1] + pacc;
      }
    float s = (float)pacc[0] + (float)pacc[1];
#pragma unroll
    for (int off = 32; off > 0; off >>= 1) s += __shfl_xor(s, off, 64);
    if (l == 0) outg[(size_t)(b0 + bp) * NN + n] = s + fcb;
    // prefetch must land before next iteration's slab reads
    asm volatile("s_waitcnt vmcnt(0)" ::: "memory");
    __builtin_amdgcn_sched_barrier(0);
  }
}

// ---------------------------------------------------------------------------
extern "C" void kernel_launch(void* const* d_in, const int* in_sizes, int n_in,
                              void* d_out, int out_size, void* d_ws, size_t ws_size,
                              hipStream_t stream) {
  const float* xg   = (const float*)d_in[0];
  const float* adjg = (const float*)d_in[1];
  const float* w1g  = (const float*)d_in[2];
  const float* b1g  = (const float*)d_in[3];
  const float* w2g  = (const float*)d_in[4];
  const float* b2g  = (const float*)d_in[5];
  const float* twg  = (const float*)d_in[6];
  const float* tbg  = (const float*)d_in[7];
  const float* fwg  = (const float*)d_in[8];
  const float* fbg  = (const float*)d_in[9];
  float* outg = (float*)d_out;

  char* ws = (char*)d_ws;
  float* Sg = (float*)ws;                      // 4,194,304 B
  u16* adjb = (u16*)(ws + 4194304);            //   524,288 B
  u16* w2t  = (u16*)(ws + 4718592);            //     8,192 B (4KB used)
  u16* Wb   = (u16*)(ws + 4726784);            // 12,582,912 B
  const size_t fixedB = 17309696;
  int CB = 32;
  while (CB > 1 && fixedB + (size_t)CB * 4194304ull > ws_size) CB >>= 1;
  u16* H2g = (u16*)(ws + fixedB);              // CB*4096 cols x 512 rows
  u16* xh  = H2g;  // xh (2MB) overlaps H2: dead before first k2 write
  const int Nc = CB * 4096;

  kcvt_adj<<<1024, 256, 0, stream>>>(adjg, adjb);
  kcvt_w2t<<<8, 256, 0, stream>>>(w2g, w2t);
  kcvt_w<<<512, 256, 0, stream>>>(twg, Wb);
  kcvt_x<<<4096, 256, 0, stream>>>(xg, xh);
  k0h<<<dim3(16, 4), 256, 0, stream>>>(xh, adjb, Sg);
  for (int b0 = 0; b0 < BB; b0 += CB) {
    k2_fused<<<dim3(4, Nc / 128), 256, 0, stream>>>(adjb, Sg, w1g, b1g, w2t, b2g,
                                                    H2g, Nc, b0);
    k3_tcn<<<dim3(NN), 256, 0, stream>>>(H2g, Wb, tbg, fwg, fbg, outg, b0, Nc, CB);
  }
}

// Round 2
// 195.235 us; speedup vs baseline: 1.3177x; 1.2158x over previous
//
#include <hip/hip_runtime.h>
#include <hip/hip_bf16.h>

#define BB 32
#define TT 64
#define NN 512
#define HH 64

using u16 = unsigned short;
using u32 = unsigned int;
typedef _Float16 f16x8 __attribute__((ext_vector_type(8)));
typedef _Float16 f16x2h __attribute__((ext_vector_type(2)));
typedef __fp16 fp16x2 __attribute__((ext_vector_type(2)));
typedef __attribute__((ext_vector_type(4))) float f32x4;

__device__ __forceinline__ u16 f2h_bits(float f) {
  _Float16 h = (_Float16)f;  // v_cvt_f16_f32, RNE, 1 instr
  u16 u; __builtin_memcpy(&u, &h, 2); return u;
}
__device__ __forceinline__ u32 pk2h(float a, float b) {  // v_cvt_pkrtz, 1 instr
  fp16x2 h = __builtin_amdgcn_cvt_pkrtz(a, b);
  u32 u; __builtin_memcpy(&u, &h, 4); return u;
}
__device__ __forceinline__ f16x2h pkh(float a, float b) {  // pkrtz -> _Float16 pair
  fp16x2 h = __builtin_amdgcn_cvt_pkrtz(a, b);
  f16x2h r; __builtin_memcpy(&r, &h, 4); return r;
}

// async global->LDS, 16B per lane; lds base wave-uniform, lane i lands at
// ldsbase + i*16; GLOBAL address is per-lane (must include lane term).
__device__ __forceinline__ void gld_lds16(const void* g, void* l) {
  __builtin_amdgcn_global_load_lds(
      (const __attribute__((address_space(1))) u32*)g,
      (__attribute__((address_space(3))) u32*)l, 16, 0, 0);
}

// ---------------------------------------------------------------------------
// conversion kernels (run once per call) — all outputs fp16
// ---------------------------------------------------------------------------
__global__ __launch_bounds__(256) void kcvt_adj(const float* __restrict__ a,
                                                u16* __restrict__ o) {
  const int i = blockIdx.x * 256 + threadIdx.x;  // 262144 total
  o[i] = f2h_bits(a[i]);
}
__global__ __launch_bounds__(256) void kcvt_x(const float* __restrict__ x,
                                              u16* __restrict__ o) {
  const int i = blockIdx.x * 256 + threadIdx.x;  // 1048576 total
  o[i] = f2h_bits(x[i]);
}
__global__ __launch_bounds__(256) void kcvt_w2t(const float* __restrict__ w2,
                                                u16* __restrict__ o) {
  const int i = blockIdx.x * 256 + threadIdx.x;  // 2048 total, o[h*32+c]
  const int h = i >> 5, c = i & 31;
  o[i] = f2h_bits(w2[c * 64 + h]);
}
// tcn_w [n][ho][hi][kk] (fp32) -> Wb [n][kk][ho][his] (f16), his = hi with its
// 16B unit XOR-swizzled by (ho&7) (involution). Coalesced read -> LDS scatter
// -> coalesced 16B write. grid (512 n), 256 threads.
__global__ __launch_bounds__(256) void kcvt_w(const float* __restrict__ tw,
                                              u16* __restrict__ o) {
  __shared__ u16 wl[3][64][64];  // [kk][ho][his], 24KB
  const int tid = threadIdx.x;
  const int n = blockIdx.x;
  const float4* pf = (const float4*)(tw + (size_t)n * 12288);
#pragma unroll
  for (int q = 0; q < 12; ++q) {
    const int fi = q * 256 + tid;
    const float4 v = pf[fi];
    const float f[4] = {v.x, v.y, v.z, v.w};
#pragma unroll
    for (int j = 0; j < 4; ++j) {
      const int e = fi * 4 + j;
      const int ho = e / 192;
      const int rem = e - ho * 192;
      const int hi = rem / 3;
      const int kk = rem - hi * 3;
      const int his = (((hi >> 3) ^ (ho & 7)) << 3) | (hi & 7);
      wl[kk][ho][his] = f2h_bits(f[j]);
    }
  }
  __syncthreads();
  const u16* src = &wl[0][0][0];
  u16* dst = o + (size_t)n * 12288;
#pragma unroll
  for (int q = 0; q < 6; ++q) {
    const int u = q * 256 + tid;  // 1536 16B units
    *(uint4*)(dst + u * 8) = *(const uint4*)(src + u * 8);
  }
}

// ---------------------------------------------------------------------------
// K0 (MFMA f16): S[bt][u] = sum_v xh[bt][v] * adjb[u][v], fp32 out.
// 128x128 tile, BK=64, gld_lds w16, XOR LDS. grid (16,4), 256 thr, 2x2 waves.
// ---------------------------------------------------------------------------
__global__ __launch_bounds__(256) void k0h(const u16* __restrict__ A,
                                           const u16* __restrict__ Bm,
                                           float* __restrict__ Sg) {
  __shared__ __align__(16) char smem[32768];  // As 16KB | Bs 16KB
  const int tid = threadIdx.x;
  const int w = tid >> 6, l = tid & 63;
  const int quad = l >> 4, lr = l & 15;
  const int m0 = blockIdx.x * 128, n0 = blockIdx.y * 128;
  const int wm = w >> 1, wn = w & 1;
  const int rB = w * 8 + (l >> 3);
  const int uu = l & 7;
  const u16* agp[4]; const u16* bgp[4];
#pragma unroll
  for (int c = 0; c < 4; ++c) {
    const int r = rB + c * 32;
    agp[c] = A + (size_t)(m0 + r) * 512 + ((uu ^ (r & 7)) * 8);
    bgp[c] = Bm + (size_t)(n0 + r) * 512 + ((uu ^ (r & 7)) * 8);
  }
  char* As = smem;
  char* Bs = smem + 16384;
  int arow[4], brow[4];
#pragma unroll
  for (int i = 0; i < 4; ++i) {
    arow[i] = (wm * 64 + i * 16 + lr) * 128;
    brow[i] = (wn * 64 + i * 16 + lr) * 128;
  }
  const f32x4 zz = {0.f, 0.f, 0.f, 0.f};
  f32x4 acc[4][4];
#pragma unroll
  for (int i = 0; i < 4; ++i)
#pragma unroll
    for (int j = 0; j < 4; ++j) acc[i][j] = zz;
  const int lx7 = lr & 7;
  for (int kt = 0; kt < 8; ++kt) {
#pragma unroll
    for (int c = 0; c < 4; ++c) {
      gld_lds16(agp[c] + kt * 64, As + (c * 32 + w * 8) * 128);
      gld_lds16(bgp[c] + kt * 64, Bs + (c * 32 + w * 8) * 128);
    }
    __syncthreads();
#pragma unroll
    for (int ks = 0; ks < 2; ++ks) {
      const int coff = (((ks * 4 + quad) ^ lx7)) * 16;
      f16x8 afr[4], bfr[4];
#pragma unroll
      for (int i = 0; i < 4; ++i) afr[i] = *(const f16x8*)(As + arow[i] + coff);
#pragma unroll
      for (int j = 0; j < 4; ++j) bfr[j] = *(const f16x8*)(Bs + brow[j] + coff);
#pragma unroll
      for (int i = 0; i < 4; ++i)
#pragma unroll
        for (int j = 0; j < 4; ++j)
          acc[i][j] = __builtin_amdgcn_mfma_f32_16x16x32_f16(afr[i], bfr[j], acc[i][j], 0, 0, 0);
    }
    __syncthreads();
  }
#pragma unroll
  for (int i = 0; i < 4; ++i) {
    const int m0r = m0 + wm * 64 + i * 16 + quad * 4;
#pragma unroll
    for (int j = 0; j < 4; ++j) {
      const int nn = n0 + wn * 64 + j * 16 + lr;
#pragma unroll
      for (int r = 0; r < 4; ++r)
        Sg[(size_t)(m0r + r) * 512 + nn] = acc[i][j][r];
    }
  }
}

// ---------------------------------------------------------------------------
// K2y (associativity rewrite): Y[u][(bt_local,c)] = sum_v adj[u][v]*h1[bt,v,c]
// where h1 = relu(w1[c]*S[bt,v]+b1[c]) is built in-LDS by pure VALU (no panel
// MFMA, no G/H2 round-trip). N = bt*32+c = CB*2048 cols (HALF of old k2's N).
// Same proven 128x128/BK=64 skeleton as old k2_fused. grid (4, Ncol/128).
// Per n-tile: 128 cols = 4 bt x 32 c; wave w builds rows [w*32,w*32+32)
// (bt = tn*4+w wave-uniform). Lane: v-octet oct=l&7, c rows crow+8k.
// ---------------------------------------------------------------------------
__global__ __launch_bounds__(256) void k2y(
    const u16* __restrict__ A, const float* __restrict__ Sg,
    const float* __restrict__ w1g, const float* __restrict__ b1g,
    u16* __restrict__ Y, int Ncol, int b0) {
  __shared__ __align__(16) char smem[32768];  // As 16KB | Bs 16KB
  const int tid = threadIdx.x;
  const int w = tid >> 6, l = tid & 63;
  const int quad = l >> 4, lr = l & 15;
  const int m0 = blockIdx.x * 128, n0 = blockIdx.y * 128;
  const int wm = w >> 1, wn = w & 1;
  const int rB = w * 8 + (l >> 3);
  const int uu = l & 7;
  const u16* agp[4];
#pragma unroll
  for (int c = 0; c < 4; ++c) {
    const int r = rB + c * 32;
    agp[c] = A + (size_t)(m0 + r) * 512 + ((uu ^ (r & 7)) * 8);
  }
  char* As = smem;
  char* Bs = smem + 16384;
  // panel-build lane constants
  const int oct = l & 7;   // v-octet (8 f16 along v)
  const int crow = l >> 3; // c base 0..7; c = crow + 8k
  const int swzW = (oct ^ crow) << 4;  // (row&7)==crow for all k
  float w1c[4], b1c[4];
#pragma unroll
  for (int k = 0; k < 4; ++k) {
    w1c[k] = w1g[crow + 8 * k];
    b1c[k] = b1g[crow + 8 * k];
  }
  // S row for this wave's bt: bt_local = tn*4 + w
  const float* sb = Sg + ((size_t)(b0 * 64) + (size_t)blockIdx.y * 4 + w) * 512;
  int arow[4], brow[4];
#pragma unroll
  for (int i = 0; i < 4; ++i) {
    arow[i] = (wm * 64 + i * 16 + lr) * 128;
    brow[i] = (wn * 64 + i * 16 + lr) * 128;
  }
  const f32x4 zz = {0.f, 0.f, 0.f, 0.f};
  f32x4 acc[4][4];
#pragma unroll
  for (int i = 0; i < 4; ++i)
#pragma unroll
    for (int j = 0; j < 4; ++j) acc[i][j] = zz;
  const int lx7 = lr & 7;
  // S prefetch for kt=0 (8 floats along v for this lane's octet)
  float4 svA = *(const float4*)(sb + oct * 8);
  float4 svB = *(const float4*)(sb + oct * 8 + 4);
  for (int kt = 0; kt < 8; ++kt) {
#pragma unroll
    for (int c = 0; c < 4; ++c)
      gld_lds16(agp[c] + kt * 64, As + (c * 32 + w * 8) * 128);
    // B-panel build: Bs[row=(w*32+c)][v-octet oct] = relu(w1[c]*S+b1[c]), f16
#pragma unroll
    for (int k = 0; k < 4; ++k) {
      const int row = w * 32 + crow + 8 * k;
      const float a = w1c[k], b = b1c[k];
      uint4 st;
      st.x = pk2h(fmaxf(a * svA.x + b, 0.f), fmaxf(a * svA.y + b, 0.f));
      st.y = pk2h(fmaxf(a * svA.z + b, 0.f), fmaxf(a * svA.w + b, 0.f));
      st.z = pk2h(fmaxf(a * svB.x + b, 0.f), fmaxf(a * svB.y + b, 0.f));
      st.w = pk2h(fmaxf(a * svB.z + b, 0.f), fmaxf(a * svB.w + b, 0.f));
      *(uint4*)(Bs + row * 128 + swzW) = st;
    }
    // prefetch next kt's S (latency covered by barrier + MFMA phase)
    if (kt < 7) {
      svA = *(const float4*)(sb + (kt + 1) * 64 + oct * 8);
      svB = *(const float4*)(sb + (kt + 1) * 64 + oct * 8 + 4);
    }
    __syncthreads();
#pragma unroll
    for (int ks = 0; ks < 2; ++ks) {
      const int coff = (((ks * 4 + quad) ^ lx7)) * 16;
      f16x8 afr[4], bfr[4];
#pragma unroll
      for (int i = 0; i < 4; ++i) afr[i] = *(const f16x8*)(As + arow[i] + coff);
#pragma unroll
      for (int j = 0; j < 4; ++j) bfr[j] = *(const f16x8*)(Bs + brow[j] + coff);
#pragma unroll
      for (int i = 0; i < 4; ++i)
#pragma unroll
        for (int j = 0; j < 4; ++j)
          acc[i][j] = __builtin_amdgcn_mfma_f32_16x16x32_f16(afr[i], bfr[j], acc[i][j], 0, 0, 0);
    }
    __syncthreads();
  }
  // epilogue: plain row-major Y f16 store (no bias/relu here — Y is linear)
#pragma unroll
  for (int i = 0; i < 4; ++i) {
    const int u0r = m0 + wm * 64 + i * 16 + quad * 4;
#pragma unroll
    for (int j = 0; j < 4; ++j) {
      const int col = n0 + wn * 64 + j * 16 + lr;
#pragma unroll
      for (int r = 0; r < 4; ++r)
        Y[(size_t)(u0r + r) * Ncol + col] = f2h_bits(acc[i][j][r]);
    }
  }
}

// ---------------------------------------------------------------------------
// K3 (MFMA, fp16, w2-fused): grid (NN) x 4 waves. Per bp: stage Y-slab
// [64t][32c] (4KB, linear, gld_lds) -> 16 MFMAs with w2^T frags ->
// relu(+b2) -> repack f16 into myl ([tc][h], XOR-swizzled) -> TCN phase
// (unchanged) -> FC epilogue (unchanged). Y prefetch issued right after the
// 4 b-frag ds_reads drain; ~2500 cyc of MFMA/VALU cover HBM latency before
// the end-of-iter vmcnt(0). Halves k3's HBM read vs the H2 path.
// ---------------------------------------------------------------------------
__global__ __launch_bounds__(256, 2) void k3_tcn(const u16* __restrict__ Yg,
                                                 const u16* __restrict__ Wb,
                                                 const u16* __restrict__ w2t,
                                                 const float* __restrict__ b2g,
                                                 const float* __restrict__ tbg,
                                                 const float* __restrict__ fwg,
                                                 const float* __restrict__ fbg,
                                                 float* __restrict__ outg,
                                                 int b0, int NcY, int CBcur) {
  __shared__ __align__(16) char wlds[24576];
  __shared__ __align__(16) char ylds_s[4][4096];
  __shared__ __align__(16) char myl_s[4][8192];
  const int tid = threadIdx.x;
  const int n = blockIdx.x;
  const int w = tid >> 6, l = tid & 63;
  const int quad = l >> 4, lr = l & 15;
  const u16* Wp = Wb + (size_t)n * 12288;
#pragma unroll
  for (int c = 0; c < 6; ++c)
    gld_lds16(Wp + (c * 4 + w) * 512 + (size_t)l * 8, wlds + (c * 4 + w) * 1024);
  // w2^T A-fragments (same layout as old k2's wf)
  f16x8 wf[4];
#pragma unroll
  for (int i = 0; i < 4; ++i)
    wf[i] = *(const f16x8*)(w2t + (i * 16 + lr) * 32 + quad * 8);
  float b2v[4][4];
#pragma unroll
  for (int i = 0; i < 4; ++i)
#pragma unroll
    for (int r = 0; r < 4; ++r) b2v[i][r] = b2g[i * 16 + quad * 4 + r];
  float tbv[4][4];
#pragma unroll
  for (int i = 0; i < 4; ++i)
#pragma unroll
    for (int r = 0; r < 4; ++r) tbv[i][r] = tbg[n * 64 + i * 16 + quad * 4 + r];
  f16x2h fwh[16][2];
#pragma unroll
  for (int i = 0; i < 4; ++i)
#pragma unroll
    for (int r = 0; r < 4; ++r) {
      const float* fb = fwg + (i * 16 + quad * 4 + r) * 64 + lr;
      fwh[i * 4 + r][0] = pkh(fb[0], fb[16]);
      fwh[i * 4 + r][1] = pkh(fb[32], fb[48]);
    }
  const float fcb = fbg[0];
  f16x8 bz;
#pragma unroll
  for (int jj = 0; jj < 8; ++jj) bz[jj] = (_Float16)0.f;
  char* yl = ylds_s[w];
  char* myl = myl_s[w];
  if (w < CBcur) {
    const u16* Ys0 = Yg + (size_t)n * NcY + w * 2048;
#pragma unroll
    for (int c = 0; c < 4; ++c)
      gld_lds16(Ys0 + c * 512 + (size_t)l * 8, yl + c * 1024);
  }
  asm volatile("s_waitcnt vmcnt(0)" ::: "memory");
  __syncthreads();
  const int lx7 = lr & 7;
  const f32x4 zz = {0.f, 0.f, 0.f, 0.f};
  for (int bp = w; bp < CBcur; bp += 4) {
    const bool hasNext = (bp + 4) < CBcur;
    // b-fragments from Y-slab: B[t = j*16+lr][c = quad*8..+8]
    f16x8 byf[4];
#pragma unroll
    for (int j = 0; j < 4; ++j)
      byf[j] = *(const f16x8*)(yl + (j * 16 + lr) * 64 + quad * 16);
    asm volatile("s_waitcnt lgkmcnt(0)" ::: "memory");
    __builtin_amdgcn_sched_barrier(0);
    // yl fully consumed into regs -> async prefetch next Y-slab into it
    if (hasNext) {
      const u16* Yn = Yg + (size_t)n * NcY + (bp + 4) * 2048;
#pragma unroll
      for (int c = 0; c < 4; ++c)
        gld_lds16(Yn + c * 512 + (size_t)l * 8, yl + c * 1024);
    }
    // h2 = relu(Y@w2 + b2): D[h = i*16+quad*4+r][t = j*16+lr]
#pragma unroll
    for (int i = 0; i < 4; ++i) {
      const int un = ((i * 2 + (quad >> 1)) ^ lx7) << 4;
#pragma unroll
      for (int j = 0; j < 4; ++j) {
        f32x4 p = __builtin_amdgcn_mfma_f32_16x16x32_f16(wf[i], byf[j], zz, 0, 0, 0);
        const float v0 = fmaxf(p[0] + b2v[i][0], 0.f);
        const float v1 = fmaxf(p[1] + b2v[i][1], 0.f);
        const float v2 = fmaxf(p[2] + b2v[i][2], 0.f);
        const float v3 = fmaxf(p[3] + b2v[i][3], 0.f);
        uint2 st;
        st.x = pk2h(v0, v1);
        st.y = pk2h(v2, v3);
        *(uint2*)(myl + (j * 16 + lr) * 128 + un + ((quad & 1) << 3)) = st;
      }
    }
    asm volatile("s_waitcnt lgkmcnt(0)" ::: "memory");
    __builtin_amdgcn_sched_barrier(0);
    // TCN phase (unchanged): reads wlds (W) + myl (h2 slab)
    f32x4 acc[4][4];
#pragma unroll
    for (int i = 0; i < 4; ++i)
#pragma unroll
      for (int j = 0; j < 4; ++j) acc[i][j] = zz;
#pragma unroll
    for (int ks = 0; ks < 2; ++ks)
#pragma unroll
      for (int kk = 0; kk < 3; ++kk) {
        const int usw = ((ks * 4 + quad) ^ lx7) << 4;
        f16x8 afr[4], bfr[4];
#pragma unroll
        for (int i = 0; i < 4; ++i)
          afr[i] = *(const f16x8*)(wlds + kk * 8192 + (i * 16 + lr) * 128 + usw);
#pragma unroll
        for (int j = 0; j < 4; ++j) {
          const int tau = j * 16 + lr + kk - 1;
          const int tc = min(max(tau, 0), 63);
          const int off = tc * 128 + (((ks * 4 + quad) ^ (tc & 7)) << 4);
          const f16x8 v = *(const f16x8*)(myl + off);
          bfr[j] = (tau == tc) ? v : bz;
        }
#pragma unroll
        for (int i = 0; i < 4; ++i)
#pragma unroll
          for (int j = 0; j < 4; ++j)
            acc[i][j] = __builtin_amdgcn_mfma_f32_16x16x32_f16(afr[i], bfr[j],
                                                               acc[i][j], 0, 0, 0);
      }
    // FC epilogue (pure-register; covers part of the prefetch latency)
    f16x2h pacc;
    pacc[0] = (_Float16)0.f; pacc[1] = (_Float16)0.f;
#pragma unroll
    for (int i = 0; i < 4; ++i)
#pragma unroll
      for (int r = 0; r < 4; ++r) {
        const float v0 = fmaxf(acc[i][0][r] + tbv[i][r], 0.f);
        const float v1 = fmaxf(acc[i][1][r] + tbv[i][r], 0.f);
        const float v2 = fmaxf(acc[i][2][r] + tbv[i][r], 0.f);
        const float v3 = fmaxf(acc[i][3][r] + tbv[i][r], 0.f);
        pacc = pkh(v0, v1) * fwh[i * 4 + r][0] + pacc;
        pacc = pkh(v2, v3) * fwh[i * 4 + r][1] + pacc;
      }
    float s = (float)pacc[0] + (float)pacc[1];
#pragma unroll
    for (int off = 32; off > 0; off >>= 1) s += __shfl_xor(s, off, 64);
    if (l == 0) outg[(size_t)(b0 + bp) * NN + n] = s + fcb;
    // prefetch must land before next iteration's byf reads
    if (hasNext) {
      asm volatile("s_waitcnt vmcnt(0)" ::: "memory");
      __builtin_amdgcn_sched_barrier(0);
    }
  }
}

// ---------------------------------------------------------------------------
extern "C" void kernel_launch(void* const* d_in, const int* in_sizes, int n_in,
                              void* d_out, int out_size, void* d_ws, size_t ws_size,
                              hipStream_t stream) {
  const float* xg   = (const float*)d_in[0];
  const float* adjg = (const float*)d_in[1];
  const float* w1g  = (const float*)d_in[2];
  const float* b1g  = (const float*)d_in[3];
  const float* w2g  = (const float*)d_in[4];
  const float* b2g  = (const float*)d_in[5];
  const float* twg  = (const float*)d_in[6];
  const float* tbg  = (const float*)d_in[7];
  const float* fwg  = (const float*)d_in[8];
  const float* fbg  = (const float*)d_in[9];
  float* outg = (float*)d_out;

  char* ws = (char*)d_ws;
  float* Sg = (float*)ws;                      // 4,194,304 B
  u16* adjb = (u16*)(ws + 4194304);            //   524,288 B
  u16* w2t  = (u16*)(ws + 4718592);            //     8,192 B (4KB used)
  u16* Wb   = (u16*)(ws + 4726784);            // 12,582,912 B
  const size_t fixedB = 17309696;
  int CB = 32;
  while (CB > 1 && fixedB + (size_t)CB * 2097152ull > ws_size) CB >>= 1;
  u16* Yg = (u16*)(ws + fixedB);               // 512 rows x CB*2048 cols, f16
  u16* xh = Yg;  // xh (2MB) overlaps Yg: dead before first k2y write
  const int Ncol = CB * 2048;

  kcvt_adj<<<1024, 256, 0, stream>>>(adjg, adjb);
  kcvt_w2t<<<8, 256, 0, stream>>>(w2g, w2t);
  kcvt_w<<<512, 256, 0, stream>>>(twg, Wb);
  kcvt_x<<<4096, 256, 0, stream>>>(xg, xh);
  k0h<<<dim3(16, 4), 256, 0, stream>>>(xh, adjb, Sg);
  for (int b0 = 0; b0 < BB; b0 += CB) {
    k2y<<<dim3(4, CB * 16), 256, 0, stream>>>(adjb, Sg, w1g, b1g, Yg, Ncol, b0);
    k3_tcn<<<dim3(NN), 256, 0, stream>>>(Yg, Wb, w2t, b2g, tbg, fwg, fbg, outg,
                                         b0, Ncol, CB);
  }
}

// Round 3
// 187.048 us; speedup vs baseline: 1.3754x; 1.0438x over previous
//
#include <hip/hip_runtime.h>
#include <hip/hip_bf16.h>

#define BB 32
#define TT 64
#define NN 512
#define HH 64

using u16 = unsigned short;
using u32 = unsigned int;
typedef _Float16 f16x8 __attribute__((ext_vector_type(8)));
typedef _Float16 f16x2h __attribute__((ext_vector_type(2)));
typedef __fp16 fp16x2 __attribute__((ext_vector_type(2)));
typedef __attribute__((ext_vector_type(4))) float f32x4;

__device__ __forceinline__ u16 f2h_bits(float f) {
  _Float16 h = (_Float16)f;  // v_cvt_f16_f32, RNE, 1 instr
  u16 u; __builtin_memcpy(&u, &h, 2); return u;
}
__device__ __forceinline__ u32 pk2h(float a, float b) {  // v_cvt_pkrtz, 1 instr
  fp16x2 h = __builtin_amdgcn_cvt_pkrtz(a, b);
  u32 u; __builtin_memcpy(&u, &h, 4); return u;
}
__device__ __forceinline__ f16x2h pkh(float a, float b) {  // pkrtz -> _Float16 pair
  fp16x2 h = __builtin_amdgcn_cvt_pkrtz(a, b);
  f16x2h r; __builtin_memcpy(&r, &h, 4); return r;
}

// async global->LDS, 16B per lane; lds base wave-uniform, lane i lands at
// ldsbase + i*16; GLOBAL address is per-lane (must include lane term).
__device__ __forceinline__ void gld_lds16(const void* g, void* l) {
  __builtin_amdgcn_global_load_lds(
      (const __attribute__((address_space(1))) u32*)g,
      (__attribute__((address_space(3))) u32*)l, 16, 0, 0);
}

// ---------------------------------------------------------------------------
// conversion kernels (run once per call) — all outputs fp16
// ---------------------------------------------------------------------------
__global__ __launch_bounds__(256) void kcvt_adj(const float* __restrict__ a,
                                                u16* __restrict__ o) {
  const int i = blockIdx.x * 256 + threadIdx.x;  // 262144 total
  o[i] = f2h_bits(a[i]);
}
__global__ __launch_bounds__(256) void kcvt_x(const float* __restrict__ x,
                                              u16* __restrict__ o) {
  const int i = blockIdx.x * 256 + threadIdx.x;  // 1048576 total
  o[i] = f2h_bits(x[i]);
}
__global__ __launch_bounds__(256) void kcvt_w2t(const float* __restrict__ w2,
                                                u16* __restrict__ o) {
  const int i = blockIdx.x * 256 + threadIdx.x;  // 2048 total, o[h*32+c]
  const int h = i >> 5, c = i & 31;
  o[i] = f2h_bits(w2[c * 64 + h]);
}
// tcn_w [n][ho][hi][kk] (fp32) -> Wb [n][kk][ho][his] (f16), his = hi with its
// 16B unit XOR-swizzled by (ho&7) (involution). Coalesced read -> LDS scatter
// -> coalesced 16B write. grid (512 n), 256 threads.
__global__ __launch_bounds__(256) void kcvt_w(const float* __restrict__ tw,
                                              u16* __restrict__ o) {
  __shared__ u16 wl[3][64][64];  // [kk][ho][his], 24KB
  const int tid = threadIdx.x;
  const int n = blockIdx.x;
  const float4* pf = (const float4*)(tw + (size_t)n * 12288);
#pragma unroll
  for (int q = 0; q < 12; ++q) {
    const int fi = q * 256 + tid;
    const float4 v = pf[fi];
    const float f[4] = {v.x, v.y, v.z, v.w};
#pragma unroll
    for (int j = 0; j < 4; ++j) {
      const int e = fi * 4 + j;
      const int ho = e / 192;
      const int rem = e - ho * 192;
      const int hi = rem / 3;
      const int kk = rem - hi * 3;
      const int his = (((hi >> 3) ^ (ho & 7)) << 3) | (hi & 7);
      wl[kk][ho][his] = f2h_bits(f[j]);
    }
  }
  __syncthreads();
  const u16* src = &wl[0][0][0];
  u16* dst = o + (size_t)n * 12288;
#pragma unroll
  for (int q = 0; q < 6; ++q) {
    const int u = q * 256 + tid;  // 1536 16B units
    *(uint4*)(dst + u * 8) = *(const uint4*)(src + u * 8);
  }
}

// ---------------------------------------------------------------------------
// K0 (MFMA f16): S[bt][u] = sum_v xh[bt][v] * adjb[u][v], fp32 out.
// 128x128 tile, BK=64, gld_lds w16, XOR LDS. grid (16,4), 256 thr, 2x2 waves.
// ---------------------------------------------------------------------------
__global__ __launch_bounds__(256) void k0h(const u16* __restrict__ A,
                                           const u16* __restrict__ Bm,
                                           float* __restrict__ Sg) {
  __shared__ __align__(16) char smem[32768];  // As 16KB | Bs 16KB
  const int tid = threadIdx.x;
  const int w = tid >> 6, l = tid & 63;
  const int quad = l >> 4, lr = l & 15;
  const int m0 = blockIdx.x * 128, n0 = blockIdx.y * 128;
  const int wm = w >> 1, wn = w & 1;
  const int rB = w * 8 + (l >> 3);
  const int uu = l & 7;
  const u16* agp[4]; const u16* bgp[4];
#pragma unroll
  for (int c = 0; c < 4; ++c) {
    const int r = rB + c * 32;
    agp[c] = A + (size_t)(m0 + r) * 512 + ((uu ^ (r & 7)) * 8);
    bgp[c] = Bm + (size_t)(n0 + r) * 512 + ((uu ^ (r & 7)) * 8);
  }
  char* As = smem;
  char* Bs = smem + 16384;
  int arow[4], brow[4];
#pragma unroll
  for (int i = 0; i < 4; ++i) {
    arow[i] = (wm * 64 + i * 16 + lr) * 128;
    brow[i] = (wn * 64 + i * 16 + lr) * 128;
  }
  const f32x4 zz = {0.f, 0.f, 0.f, 0.f};
  f32x4 acc[4][4];
#pragma unroll
  for (int i = 0; i < 4; ++i)
#pragma unroll
    for (int j = 0; j < 4; ++j) acc[i][j] = zz;
  const int lx7 = lr & 7;
  for (int kt = 0; kt < 8; ++kt) {
#pragma unroll
    for (int c = 0; c < 4; ++c) {
      gld_lds16(agp[c] + kt * 64, As + (c * 32 + w * 8) * 128);
      gld_lds16(bgp[c] + kt * 64, Bs + (c * 32 + w * 8) * 128);
    }
    __syncthreads();
#pragma unroll
    for (int ks = 0; ks < 2; ++ks) {
      const int coff = (((ks * 4 + quad) ^ lx7)) * 16;
      f16x8 afr[4], bfr[4];
#pragma unroll
      for (int i = 0; i < 4; ++i) afr[i] = *(const f16x8*)(As + arow[i] + coff);
#pragma unroll
      for (int j = 0; j < 4; ++j) bfr[j] = *(const f16x8*)(Bs + brow[j] + coff);
#pragma unroll
      for (int i = 0; i < 4; ++i)
#pragma unroll
        for (int j = 0; j < 4; ++j)
          acc[i][j] = __builtin_amdgcn_mfma_f32_16x16x32_f16(afr[i], bfr[j], acc[i][j], 0, 0, 0);
    }
    __syncthreads();
  }
#pragma unroll
  for (int i = 0; i < 4; ++i) {
    const int m0r = m0 + wm * 64 + i * 16 + quad * 4;
#pragma unroll
    for (int j = 0; j < 4; ++j) {
      const int nn = n0 + wn * 64 + j * 16 + lr;
#pragma unroll
      for (int r = 0; r < 4; ++r)
        Sg[(size_t)(m0r + r) * 512 + nn] = acc[i][j][r];
    }
  }
}

// ---------------------------------------------------------------------------
// K2y (R3: double-buffered single-barrier schedule): Y = adj @ h1,
// h1 = relu(w1[c]*S[bt,v]+b1[c]) built in-LDS by VALU.
// Per kt: {issue gld_lds As[nxt]; VALU-build Bs[nxt]; MFMA on [cur]} -> one
// __syncthreads. Writes touch only [nxt], reads only [cur] -> race-free.
// Panel-build + A-load latency now hide under the MFMA phase (was: 2 barriers
// per kt serializing VALU panel vs MFMA -> MfmaUtil 21%/VALU 42%).
// LDS 64KB: As0|As1|Bs0|Bs1. grid (4, Ncol/128), 256 thr, 2x2 waves.
// ---------------------------------------------------------------------------
__global__ __launch_bounds__(256) void k2y(
    const u16* __restrict__ A, const float* __restrict__ Sg,
    const float* __restrict__ w1g, const float* __restrict__ b1g,
    u16* __restrict__ Y, int Ncol, int b0) {
  __shared__ __align__(16) char smem[65536];  // As0 16K | As1 16K | Bs0 16K | Bs1 16K
  const int tid = threadIdx.x;
  const int w = tid >> 6, l = tid & 63;
  const int quad = l >> 4, lr = l & 15;
  const int m0 = blockIdx.x * 128, n0 = blockIdx.y * 128;
  const int wm = w >> 1, wn = w & 1;
  const int rB = w * 8 + (l >> 3);
  const int uu = l & 7;
  const u16* agp[4];
#pragma unroll
  for (int c = 0; c < 4; ++c) {
    const int r = rB + c * 32;
    agp[c] = A + (size_t)(m0 + r) * 512 + ((uu ^ (r & 7)) * 8);
  }
  // panel-build lane constants
  const int oct = l & 7;   // v-octet (8 f16 along v)
  const int crow = l >> 3; // c base 0..7; c = crow + 8k
  const int swzW = (oct ^ crow) << 4;  // (row&7)==crow for all k
  float w1c[4], b1c[4];
#pragma unroll
  for (int k = 0; k < 4; ++k) {
    w1c[k] = w1g[crow + 8 * k];
    b1c[k] = b1g[crow + 8 * k];
  }
  // S row for this wave's bt: bt_local = tn*4 + w
  const float* sb = Sg + ((size_t)(b0 * 64) + (size_t)blockIdx.y * 4 + w) * 512;
  int arow[4], brow[4];
#pragma unroll
  for (int i = 0; i < 4; ++i) {
    arow[i] = (wm * 64 + i * 16 + lr) * 128;
    brow[i] = (wn * 64 + i * 16 + lr) * 128;
  }
  const f32x4 zz = {0.f, 0.f, 0.f, 0.f};
  f32x4 acc[4][4];
#pragma unroll
  for (int i = 0; i < 4; ++i)
#pragma unroll
    for (int j = 0; j < 4; ++j) acc[i][j] = zz;
  const int lx7 = lr & 7;
  const int prow = w * 32 + crow;  // panel row base for this lane

  // ---- prologue: stage As0, build Bs0 from S(0), issue S(1) loads ----
  float4 svA = *(const float4*)(sb + oct * 8);
  float4 svB = *(const float4*)(sb + oct * 8 + 4);
#pragma unroll
  for (int c = 0; c < 4; ++c)
    gld_lds16(agp[c], smem + (c * 32 + w * 8) * 128);
#pragma unroll
  for (int k = 0; k < 4; ++k) {
    const float a = w1c[k], b = b1c[k];
    uint4 st;
    st.x = pk2h(fmaxf(a * svA.x + b, 0.f), fmaxf(a * svA.y + b, 0.f));
    st.y = pk2h(fmaxf(a * svA.z + b, 0.f), fmaxf(a * svA.w + b, 0.f));
    st.z = pk2h(fmaxf(a * svB.x + b, 0.f), fmaxf(a * svB.y + b, 0.f));
    st.w = pk2h(fmaxf(a * svB.z + b, 0.f), fmaxf(a * svB.w + b, 0.f));
    *(uint4*)(smem + 32768 + (prow + 8 * k) * 128 + swzW) = st;
  }
  svA = *(const float4*)(sb + 64 + oct * 8);
  svB = *(const float4*)(sb + 64 + oct * 8 + 4);
  __syncthreads();

  // ---- main loop: one barrier per kt ----
  for (int kt = 0; kt < 8; ++kt) {
    const int cur = kt & 1, nxt = cur ^ 1;
    char* Asc = smem + cur * 16384;
    char* Bsc = smem + 32768 + cur * 16384;
    if (kt < 7) {
      char* Asn = smem + nxt * 16384;
      char* Bsn = smem + 32768 + nxt * 16384;
#pragma unroll
      for (int c = 0; c < 4; ++c)
        gld_lds16(agp[c] + (kt + 1) * 64, Asn + (c * 32 + w * 8) * 128);
      // build panel(kt+1) from sv (= S(kt+1))
#pragma unroll
      for (int k = 0; k < 4; ++k) {
        const float a = w1c[k], b = b1c[k];
        uint4 st;
        st.x = pk2h(fmaxf(a * svA.x + b, 0.f), fmaxf(a * svA.y + b, 0.f));
        st.y = pk2h(fmaxf(a * svA.z + b, 0.f), fmaxf(a * svA.w + b, 0.f));
        st.z = pk2h(fmaxf(a * svB.x + b, 0.f), fmaxf(a * svB.y + b, 0.f));
        st.w = pk2h(fmaxf(a * svB.z + b, 0.f), fmaxf(a * svB.w + b, 0.f));
        *(uint4*)(Bsn + (prow + 8 * k) * 128 + swzW) = st;
      }
      if (kt < 6) {  // issue S(kt+2) loads (consumed next iter)
        svA = *(const float4*)(sb + (kt + 2) * 64 + oct * 8);
        svB = *(const float4*)(sb + (kt + 2) * 64 + oct * 8 + 4);
      }
    }
    // MFMA phase on [cur]
#pragma unroll
    for (int ks = 0; ks < 2; ++ks) {
      const int coff = (((ks * 4 + quad) ^ lx7)) * 16;
      f16x8 afr[4], bfr[4];
#pragma unroll
      for (int i = 0; i < 4; ++i) afr[i] = *(const f16x8*)(Asc + arow[i] + coff);
#pragma unroll
      for (int j = 0; j < 4; ++j) bfr[j] = *(const f16x8*)(Bsc + brow[j] + coff);
#pragma unroll
      for (int i = 0; i < 4; ++i)
#pragma unroll
        for (int j = 0; j < 4; ++j)
          acc[i][j] = __builtin_amdgcn_mfma_f32_16x16x32_f16(afr[i], bfr[j], acc[i][j], 0, 0, 0);
    }
    if (kt < 7) __syncthreads();
  }
  // epilogue: plain row-major Y f16 store (no bias/relu here — Y is linear)
#pragma unroll
  for (int i = 0; i < 4; ++i) {
    const int u0r = m0 + wm * 64 + i * 16 + quad * 4;
#pragma unroll
    for (int j = 0; j < 4; ++j) {
      const int col = n0 + wn * 64 + j * 16 + lr;
#pragma unroll
      for (int r = 0; r < 4; ++r)
        Y[(size_t)(u0r + r) * Ncol + col] = f2h_bits(acc[i][j][r]);
    }
  }
}

// ---------------------------------------------------------------------------
// K3 (MFMA, fp16, w2-fused): grid (NN) x 4 waves. Per bp: stage Y-slab
// [64t][32c] (4KB, linear, gld_lds) -> 16 MFMAs with w2^T frags ->
// relu(+b2) -> repack f16 into myl ([tc][h], XOR-swizzled) -> TCN phase
// (unchanged) -> FC epilogue (unchanged). Y prefetch issued right after the
// 4 b-frag ds_reads drain; ~2500 cyc of MFMA/VALU cover HBM latency before
// the end-of-iter vmcnt(0). Halves k3's HBM read vs the H2 path.
// ---------------------------------------------------------------------------
__global__ __launch_bounds__(256, 2) void k3_tcn(const u16* __restrict__ Yg,
                                                 const u16* __restrict__ Wb,
                                                 const u16* __restrict__ w2t,
                                                 const float* __restrict__ b2g,
                                                 const float* __restrict__ tbg,
                                                 const float* __restrict__ fwg,
                                                 const float* __restrict__ fbg,
                                                 float* __restrict__ outg,
                                                 int b0, int NcY, int CBcur) {
  __shared__ __align__(16) char wlds[24576];
  __shared__ __align__(16) char ylds_s[4][4096];
  __shared__ __align__(16) char myl_s[4][8192];
  const int tid = threadIdx.x;
  const int n = blockIdx.x;
  const int w = tid >> 6, l = tid & 63;
  const int quad = l >> 4, lr = l & 15;
  const u16* Wp = Wb + (size_t)n * 12288;
#pragma unroll
  for (int c = 0; c < 6; ++c)
    gld_lds16(Wp + (c * 4 + w) * 512 + (size_t)l * 8, wlds + (c * 4 + w) * 1024);
  // w2^T A-fragments (same layout as old k2's wf)
  f16x8 wf[4];
#pragma unroll
  for (int i = 0; i < 4; ++i)
    wf[i] = *(const f16x8*)(w2t + (i * 16 + lr) * 32 + quad * 8);
  float b2v[4][4];
#pragma unroll
  for (int i = 0; i < 4; ++i)
#pragma unroll
    for (int r = 0; r < 4; ++r) b2v[i][r] = b2g[i * 16 + quad * 4 + r];
  float tbv[4][4];
#pragma unroll
  for (int i = 0; i < 4; ++i)
#pragma unroll
    for (int r = 0; r < 4; ++r) tbv[i][r] = tbg[n * 64 + i * 16 + quad * 4 + r];
  f16x2h fwh[16][2];
#pragma unroll
  for (int i = 0; i < 4; ++i)
#pragma unroll
    for (int r = 0; r < 4; ++r) {
      const float* fb = fwg + (i * 16 + quad * 4 + r) * 64 + lr;
      fwh[i * 4 + r][0] = pkh(fb[0], fb[16]);
      fwh[i * 4 + r][1] = pkh(fb[32], fb[48]);
    }
  const float fcb = fbg[0];
  f16x8 bz;
#pragma unroll
  for (int jj = 0; jj < 8; ++jj) bz[jj] = (_Float16)0.f;
  char* yl = ylds_s[w];
  char* myl = myl_s[w];
  if (w < CBcur) {
    const u16* Ys0 = Yg + (size_t)n * NcY + w * 2048;
#pragma unroll
    for (int c = 0; c < 4; ++c)
      gld_lds16(Ys0 + c * 512 + (size_t)l * 8, yl + c * 1024);
  }
  asm volatile("s_waitcnt vmcnt(0)" ::: "memory");
  __syncthreads();
  const int lx7 = lr & 7;
  const f32x4 zz = {0.f, 0.f, 0.f, 0.f};
  for (int bp = w; bp < CBcur; bp += 4) {
    const bool hasNext = (bp + 4) < CBcur;
    // b-fragments from Y-slab: B[t = j*16+lr][c = quad*8..+8]
    f16x8 byf[4];
#pragma unroll
    for (int j = 0; j < 4; ++j)
      byf[j] = *(const f16x8*)(yl + (j * 16 + lr) * 64 + quad * 16);
    asm volatile("s_waitcnt lgkmcnt(0)" ::: "memory");
    __builtin_amdgcn_sched_barrier(0);
    // yl fully consumed into regs -> async prefetch next Y-slab into it
    if (hasNext) {
      const u16* Yn = Yg + (size_t)n * NcY + (bp + 4) * 2048;
#pragma unroll
      for (int c = 0; c < 4; ++c)
        gld_lds16(Yn + c * 512 + (size_t)l * 8, yl + c * 1024);
    }
    // h2 = relu(Y@w2 + b2): D[h = i*16+quad*4+r][t = j*16+lr]
#pragma unroll
    for (int i = 0; i < 4; ++i) {
      const int un = ((i * 2 + (quad >> 1)) ^ lx7) << 4;
#pragma unroll
      for (int j = 0; j < 4; ++j) {
        f32x4 p = __builtin_amdgcn_mfma_f32_16x16x32_f16(wf[i], byf[j], zz, 0, 0, 0);
        const float v0 = fmaxf(p[0] + b2v[i][0], 0.f);
        const float v1 = fmaxf(p[1] + b2v[i][1], 0.f);
        const float v2 = fmaxf(p[2] + b2v[i][2], 0.f);
        const float v3 = fmaxf(p[3] + b2v[i][3], 0.f);
        uint2 st;
        st.x = pk2h(v0, v1);
        st.y = pk2h(v2, v3);
        *(uint2*)(myl + (j * 16 + lr) * 128 + un + ((quad & 1) << 3)) = st;
      }
    }
    asm volatile("s_waitcnt lgkmcnt(0)" ::: "memory");
    __builtin_amdgcn_sched_barrier(0);
    // TCN phase (unchanged): reads wlds (W) + myl (h2 slab)
    f32x4 acc[4][4];
#pragma unroll
    for (int i = 0; i < 4; ++i)
#pragma unroll
      for (int j = 0; j < 4; ++j) acc[i][j] = zz;
#pragma unroll
    for (int ks = 0; ks < 2; ++ks)
#pragma unroll
      for (int kk = 0; kk < 3; ++kk) {
        const int usw = ((ks * 4 + quad) ^ lx7) << 4;
        f16x8 afr[4], bfr[4];
#pragma unroll
        for (int i = 0; i < 4; ++i)
          afr[i] = *(const f16x8*)(wlds + kk * 8192 + (i * 16 + lr) * 128 + usw);
#pragma unroll
        for (int j = 0; j < 4; ++j) {
          const int tau = j * 16 + lr + kk - 1;
          const int tc = min(max(tau, 0), 63);
          const int off = tc * 128 + (((ks * 4 + quad) ^ (tc & 7)) << 4);
          const f16x8 v = *(const f16x8*)(myl + off);
          bfr[j] = (tau == tc) ? v : bz;
        }
#pragma unroll
        for (int i = 0; i < 4; ++i)
#pragma unroll
          for (int j = 0; j < 4; ++j)
            acc[i][j] = __builtin_amdgcn_mfma_f32_16x16x32_f16(afr[i], bfr[j],
                                                               acc[i][j], 0, 0, 0);
      }
    // FC epilogue (pure-register; covers part of the prefetch latency)
    f16x2h pacc;
    pacc[0] = (_Float16)0.f; pacc[1] = (_Float16)0.f;
#pragma unroll
    for (int i = 0; i < 4; ++i)
#pragma unroll
      for (int r = 0; r < 4; ++r) {
        const float v0 = fmaxf(acc[i][0][r] + tbv[i][r], 0.f);
        const float v1 = fmaxf(acc[i][1][r] + tbv[i][r], 0.f);
        const float v2 = fmaxf(acc[i][2][r] + tbv[i][r], 0.f);
        const float v3 = fmaxf(acc[i][3][r] + tbv[i][r], 0.f);
        pacc = pkh(v0, v1) * fwh[i * 4 + r][0] + pacc;
        pacc = pkh(v2, v3) * fwh[i * 4 + r][1] + pacc;
      }
    float s = (float)pacc[0] + (float)pacc[1];
#pragma unroll
    for (int off = 32; off > 0; off >>= 1) s += __shfl_xor(s, off, 64);
    if (l == 0) outg[(size_t)(b0 + bp) * NN + n] = s + fcb;
    // prefetch must land before next iteration's byf reads
    if (hasNext) {
      asm volatile("s_waitcnt vmcnt(0)" ::: "memory");
      __builtin_amdgcn_sched_barrier(0);
    }
  }
}

// ---------------------------------------------------------------------------
extern "C" void kernel_launch(void* const* d_in, const int* in_sizes, int n_in,
                              void* d_out, int out_size, void* d_ws, size_t ws_size,
                              hipStream_t stream) {
  const float* xg   = (const float*)d_in[0];
  const float* adjg = (const float*)d_in[1];
  const float* w1g  = (const float*)d_in[2];
  const float* b1g  = (const float*)d_in[3];
  const float* w2g  = (const float*)d_in[4];
  const float* b2g  = (const float*)d_in[5];
  const float* twg  = (const float*)d_in[6];
  const float* tbg  = (const float*)d_in[7];
  const float* fwg  = (const float*)d_in[8];
  const float* fbg  = (const float*)d_in[9];
  float* outg = (float*)d_out;

  char* ws = (char*)d_ws;
  float* Sg = (float*)ws;                      // 4,194,304 B
  u16* adjb = (u16*)(ws + 4194304);            //   524,288 B
  u16* w2t  = (u16*)(ws + 4718592);            //     8,192 B (4KB used)
  u16* Wb   = (u16*)(ws + 4726784);            // 12,582,912 B
  const size_t fixedB = 17309696;
  int CB = 32;
  while (CB > 1 && fixedB + (size_t)CB * 2097152ull > ws_size) CB >>= 1;
  u16* Yg = (u16*)(ws + fixedB);               // 512 rows x CB*2048 cols, f16
  u16* xh = Yg;  // xh (2MB) overlaps Yg: dead before first k2y write
  const int Ncol = CB * 2048;

  kcvt_adj<<<1024, 256, 0, stream>>>(adjg, adjb);
  kcvt_w2t<<<8, 256, 0, stream>>>(w2g, w2t);
  kcvt_w<<<512, 256, 0, stream>>>(twg, Wb);
  kcvt_x<<<4096, 256, 0, stream>>>(xg, xh);
  k0h<<<dim3(16, 4), 256, 0, stream>>>(xh, adjb, Sg);
  for (int b0 = 0; b0 < BB; b0 += CB) {
    k2y<<<dim3(4, CB * 16), 256, 0, stream>>>(adjb, Sg, w1g, b1g, Yg, Ncol, b0);
    k3_tcn<<<dim3(NN), 256, 0, stream>>>(Yg, Wb, w2t, b2g, tbg, fwg, fbg, outg,
                                         b0, Ncol, CB);
  }
}

// Round 4
// 185.028 us; speedup vs baseline: 1.3904x; 1.0109x over previous
//
#include <hip/hip_runtime.h>
#include <hip/hip_bf16.h>

#define BB 32
#define TT 64
#define NN 512
#define HH 64

using u16 = unsigned short;
using u32 = unsigned int;
typedef _Float16 f16x8 __attribute__((ext_vector_type(8)));
typedef _Float16 f16x2h __attribute__((ext_vector_type(2)));
typedef __fp16 fp16x2 __attribute__((ext_vector_type(2)));
typedef __attribute__((ext_vector_type(4))) float f32x4;

__device__ __forceinline__ u16 f2h_bits(float f) {
  _Float16 h = (_Float16)f;  // v_cvt_f16_f32, RNE, 1 instr
  u16 u; __builtin_memcpy(&u, &h, 2); return u;
}
__device__ __forceinline__ u32 pk2h(float a, float b) {  // v_cvt_pkrtz, 1 instr
  fp16x2 h = __builtin_amdgcn_cvt_pkrtz(a, b);
  u32 u; __builtin_memcpy(&u, &h, 4); return u;
}
__device__ __forceinline__ f16x2h pkh(float a, float b) {  // pkrtz -> _Float16 pair
  fp16x2 h = __builtin_amdgcn_cvt_pkrtz(a, b);
  f16x2h r; __builtin_memcpy(&r, &h, 4); return r;
}

// async global->LDS, 16B per lane; lds base wave-uniform, lane i lands at
// ldsbase + i*16; GLOBAL address is per-lane (must include lane term).
__device__ __forceinline__ void gld_lds16(const void* g, void* l) {
  __builtin_amdgcn_global_load_lds(
      (const __attribute__((address_space(1))) u32*)g,
      (__attribute__((address_space(3))) u32*)l, 16, 0, 0);
}

// ---------------------------------------------------------------------------
// conversion kernels (run once per call) — all outputs fp16
// ---------------------------------------------------------------------------
__global__ __launch_bounds__(256) void kcvt_adj(const float* __restrict__ a,
                                                u16* __restrict__ o) {
  const int i = blockIdx.x * 256 + threadIdx.x;  // 262144 total
  o[i] = f2h_bits(a[i]);
}
__global__ __launch_bounds__(256) void kcvt_x(const float* __restrict__ x,
                                              u16* __restrict__ o) {
  const int i = blockIdx.x * 256 + threadIdx.x;  // 1048576 total
  o[i] = f2h_bits(x[i]);
}
__global__ __launch_bounds__(256) void kcvt_w2t(const float* __restrict__ w2,
                                                u16* __restrict__ o) {
  const int i = blockIdx.x * 256 + threadIdx.x;  // 2048 total, o[h*32+c]
  const int h = i >> 5, c = i & 31;
  o[i] = f2h_bits(w2[c * 64 + h]);
}
// tcn_w [n][ho][hi][kk] (fp32) -> Wb [n][kk][ho][his] (f16), his = hi with its
// 16B unit XOR-swizzled by (ho&7) (involution). Coalesced read -> LDS scatter
// -> coalesced 16B write. grid (512 n), 256 threads.
__global__ __launch_bounds__(256) void kcvt_w(const float* __restrict__ tw,
                                              u16* __restrict__ o) {
  __shared__ u16 wl[3][64][64];  // [kk][ho][his], 24KB
  const int tid = threadIdx.x;
  const int n = blockIdx.x;
  const float4* pf = (const float4*)(tw + (size_t)n * 12288);
#pragma unroll
  for (int q = 0; q < 12; ++q) {
    const int fi = q * 256 + tid;
    const float4 v = pf[fi];
    const float f[4] = {v.x, v.y, v.z, v.w};
#pragma unroll
    for (int j = 0; j < 4; ++j) {
      const int e = fi * 4 + j;
      const int ho = e / 192;
      const int rem = e - ho * 192;
      const int hi = rem / 3;
      const int kk = rem - hi * 3;
      const int his = (((hi >> 3) ^ (ho & 7)) << 3) | (hi & 7);
      wl[kk][ho][his] = f2h_bits(f[j]);
    }
  }
  __syncthreads();
  const u16* src = &wl[0][0][0];
  u16* dst = o + (size_t)n * 12288;
#pragma unroll
  for (int q = 0; q < 6; ++q) {
    const int u = q * 256 + tid;  // 1536 16B units
    *(uint4*)(dst + u * 8) = *(const uint4*)(src + u * 8);
  }
}

// ---------------------------------------------------------------------------
// K0 (MFMA f16): S[bt][u] = sum_v xh[bt][v] * adjb[u][v], fp32 out.
// 128x128 tile, BK=64, gld_lds w16, XOR LDS. grid (16,4), 256 thr, 2x2 waves.
// ---------------------------------------------------------------------------
__global__ __launch_bounds__(256) void k0h(const u16* __restrict__ A,
                                           const u16* __restrict__ Bm,
                                           float* __restrict__ Sg) {
  __shared__ __align__(16) char smem[32768];  // As 16KB | Bs 16KB
  const int tid = threadIdx.x;
  const int w = tid >> 6, l = tid & 63;
  const int quad = l >> 4, lr = l & 15;
  const int m0 = blockIdx.x * 128, n0 = blockIdx.y * 128;
  const int wm = w >> 1, wn = w & 1;
  const int rB = w * 8 + (l >> 3);
  const int uu = l & 7;
  const u16* agp[4]; const u16* bgp[4];
#pragma unroll
  for (int c = 0; c < 4; ++c) {
    const int r = rB + c * 32;
    agp[c] = A + (size_t)(m0 + r) * 512 + ((uu ^ (r & 7)) * 8);
    bgp[c] = Bm + (size_t)(n0 + r) * 512 + ((uu ^ (r & 7)) * 8);
  }
  char* As = smem;
  char* Bs = smem + 16384;
  int arow[4], brow[4];
#pragma unroll
  for (int i = 0; i < 4; ++i) {
    arow[i] = (wm * 64 + i * 16 + lr) * 128;
    brow[i] = (wn * 64 + i * 16 + lr) * 128;
  }
  const f32x4 zz = {0.f, 0.f, 0.f, 0.f};
  f32x4 acc[4][4];
#pragma unroll
  for (int i = 0; i < 4; ++i)
#pragma unroll
    for (int j = 0; j < 4; ++j) acc[i][j] = zz;
  const int lx7 = lr & 7;
  for (int kt = 0; kt < 8; ++kt) {
#pragma unroll
    for (int c = 0; c < 4; ++c) {
      gld_lds16(agp[c] + kt * 64, As + (c * 32 + w * 8) * 128);
      gld_lds16(bgp[c] + kt * 64, Bs + (c * 32 + w * 8) * 128);
    }
    __syncthreads();
#pragma unroll
    for (int ks = 0; ks < 2; ++ks) {
      const int coff = (((ks * 4 + quad) ^ lx7)) * 16;
      f16x8 afr[4], bfr[4];
#pragma unroll
      for (int i = 0; i < 4; ++i) afr[i] = *(const f16x8*)(As + arow[i] + coff);
#pragma unroll
      for (int j = 0; j < 4; ++j) bfr[j] = *(const f16x8*)(Bs + brow[j] + coff);
#pragma unroll
      for (int i = 0; i < 4; ++i)
#pragma unroll
        for (int j = 0; j < 4; ++j)
          acc[i][j] = __builtin_amdgcn_mfma_f32_16x16x32_f16(afr[i], bfr[j], acc[i][j], 0, 0, 0);
    }
    __syncthreads();
  }
#pragma unroll
  for (int i = 0; i < 4; ++i) {
    const int m0r = m0 + wm * 64 + i * 16 + quad * 4;
#pragma unroll
    for (int j = 0; j < 4; ++j) {
      const int nn = n0 + wn * 64 + j * 16 + lr;
#pragma unroll
      for (int r = 0; r < 4; ++r)
        Sg[(size_t)(m0r + r) * 512 + nn] = acc[i][j][r];
    }
  }
}

// ---------------------------------------------------------------------------
// K2y (R4: depth-2 counted-vmcnt pipeline): Y = adj @ h1,
// h1 = relu(w1[c]*S[bt,v]+b1[c]) built in-LDS by VALU.
// Per kt, two RAW barriers, NO vmcnt(0) drain in the loop:
//   phase A: MFMA on slot[kt&1]           (ds_read; compiler counted-lgkm)
//   mid-bar (publishes "all reads of slot kt&1 done")
//   phase B: build Bs(kt+2) into slot[kt&1]  <- consuming S(kt+2); the
//            compiler's wait for S(kt+2) transitively drains gld(kt+1)
//            (issued before S(kt+2) last iter) in EVERY wave -> after the
//            end-bar, As(kt+1) is published. Then issue gld As(kt+2),
//            load S(kt+3), lgkmcnt(0), end-bar.
// Loads therefore span ~1.5 kt (>1000cyc cover) and vmcnt never drains to 0
// in the loop (m218 mechanism: counted vs drain-0 = +38-73%).
// LDS 64KB: As0|As1|Bs0|Bs1. grid (4, Ncol/128), 256 thr, 2x2 waves.
// ---------------------------------------------------------------------------
__global__ __launch_bounds__(256) void k2y(
    const u16* __restrict__ A, const float* __restrict__ Sg,
    const float* __restrict__ w1g, const float* __restrict__ b1g,
    u16* __restrict__ Y, int Ncol, int b0) {
  __shared__ __align__(16) char smem[65536];  // As0 16K | As1 16K | Bs0 16K | Bs1 16K
  const int tid = threadIdx.x;
  const int w = tid >> 6, l = tid & 63;
  const int quad = l >> 4, lr = l & 15;
  const int m0 = blockIdx.x * 128, n0 = blockIdx.y * 128;
  const int wm = w >> 1, wn = w & 1;
  const int rB = w * 8 + (l >> 3);
  const int uu = l & 7;
  const u16* agp[4];
#pragma unroll
  for (int c = 0; c < 4; ++c) {
    const int r = rB + c * 32;
    agp[c] = A + (size_t)(m0 + r) * 512 + ((uu ^ (r & 7)) * 8);
  }
  // panel-build lane constants
  const int oct = l & 7;   // v-octet (8 f16 along v)
  const int crow = l >> 3; // c base 0..7; c = crow + 8k
  const int swzW = (oct ^ crow) << 4;  // (row&7)==crow for all k
  float w1c[4], b1c[4];
#pragma unroll
  for (int k = 0; k < 4; ++k) {
    w1c[k] = w1g[crow + 8 * k];
    b1c[k] = b1g[crow + 8 * k];
  }
  // S row for this wave's bt: bt_local = tn*4 + w
  const float* sb = Sg + ((size_t)(b0 * 64) + (size_t)blockIdx.y * 4 + w) * 512;
  int arow[4], brow[4];
#pragma unroll
  for (int i = 0; i < 4; ++i) {
    arow[i] = (wm * 64 + i * 16 + lr) * 128;
    brow[i] = (wn * 64 + i * 16 + lr) * 128;
  }
  const f32x4 zz = {0.f, 0.f, 0.f, 0.f};
  f32x4 acc[4][4];
#pragma unroll
  for (int i = 0; i < 4; ++i)
#pragma unroll
    for (int j = 0; j < 4; ++j) acc[i][j] = zz;
  const int lx7 = lr & 7;
  const int prow = w * 32 + crow;  // panel row base for this lane

  // ---- prologue: build Bs(0),Bs(1); stage As(0),As(1); issue S(2) ----
#pragma unroll
  for (int t = 0; t < 2; ++t) {
    const float4 vA = *(const float4*)(sb + t * 64 + oct * 8);
    const float4 vB = *(const float4*)(sb + t * 64 + oct * 8 + 4);
    char* Bsd = smem + 32768 + t * 16384;
#pragma unroll
    for (int k = 0; k < 4; ++k) {
      const float a = w1c[k], b = b1c[k];
      uint4 st;
      st.x = pk2h(fmaxf(a * vA.x + b, 0.f), fmaxf(a * vA.y + b, 0.f));
      st.y = pk2h(fmaxf(a * vA.z + b, 0.f), fmaxf(a * vA.w + b, 0.f));
      st.z = pk2h(fmaxf(a * vB.x + b, 0.f), fmaxf(a * vB.y + b, 0.f));
      st.w = pk2h(fmaxf(a * vB.z + b, 0.f), fmaxf(a * vB.w + b, 0.f));
      *(uint4*)(Bsd + (prow + 8 * k) * 128 + swzW) = st;
    }
  }
#pragma unroll
  for (int c = 0; c < 4; ++c) {
    gld_lds16(agp[c], smem + (c * 32 + w * 8) * 128);
    gld_lds16(agp[c] + 64, smem + 16384 + (c * 32 + w * 8) * 128);
  }
  float4 svA = *(const float4*)(sb + 2 * 64 + oct * 8);
  float4 svB = *(const float4*)(sb + 2 * 64 + oct * 8 + 4);
  asm volatile("s_waitcnt vmcnt(2) lgkmcnt(0)" ::: "memory");  // drain 8 gld, keep S(2)
  __builtin_amdgcn_sched_barrier(0);
  __builtin_amdgcn_s_barrier();
  __builtin_amdgcn_sched_barrier(0);

  // ---- main loop: 2 raw barriers per kt, counted vmcnt only ----
#pragma unroll
  for (int kt = 0; kt < 8; ++kt) {
    char* Asc = smem + (kt & 1) * 16384;
    char* Bsc = smem + 32768 + (kt & 1) * 16384;
    // phase A: MFMA on slot[kt&1]
    __builtin_amdgcn_s_setprio(1);
#pragma unroll
    for (int ks = 0; ks < 2; ++ks) {
      const int coff = (((ks * 4 + quad) ^ lx7)) * 16;
      f16x8 afr[4], bfr[4];
#pragma unroll
      for (int i = 0; i < 4; ++i) afr[i] = *(const f16x8*)(Asc + arow[i] + coff);
#pragma unroll
      for (int j = 0; j < 4; ++j) bfr[j] = *(const f16x8*)(Bsc + brow[j] + coff);
#pragma unroll
      for (int i = 0; i < 4; ++i)
#pragma unroll
        for (int j = 0; j < 4; ++j)
          acc[i][j] = __builtin_amdgcn_mfma_f32_16x16x32_f16(afr[i], bfr[j], acc[i][j], 0, 0, 0);
    }
    __builtin_amdgcn_s_setprio(0);
    if (kt < 6) {
      // mid-bar: all waves done reading slot[kt&1]
      __builtin_amdgcn_sched_barrier(0);
      __builtin_amdgcn_s_barrier();
      __builtin_amdgcn_sched_barrier(0);
      // phase B: build Bs(kt+2) (consumes S(kt+2) -> compiler drains older VMEM)
#pragma unroll
      for (int k = 0; k < 4; ++k) {
        const float a = w1c[k], b = b1c[k];
        uint4 st;
        st.x = pk2h(fmaxf(a * svA.x + b, 0.f), fmaxf(a * svA.y + b, 0.f));
        st.y = pk2h(fmaxf(a * svA.z + b, 0.f), fmaxf(a * svA.w + b, 0.f));
        st.z = pk2h(fmaxf(a * svB.x + b, 0.f), fmaxf(a * svB.y + b, 0.f));
        st.w = pk2h(fmaxf(a * svB.z + b, 0.f), fmaxf(a * svB.w + b, 0.f));
        *(uint4*)(Bsc + (prow + 8 * k) * 128 + swzW) = st;
      }
      // issue As(kt+2) into the just-freed slot
#pragma unroll
      for (int c = 0; c < 4; ++c)
        gld_lds16(agp[c] + (kt + 2) * 64, Asc + (c * 32 + w * 8) * 128);
      if (kt < 5) {  // S(kt+3) for next phase B
        svA = *(const float4*)(sb + (kt + 3) * 64 + oct * 8);
        svB = *(const float4*)(sb + (kt + 3) * 64 + oct * 8 + 4);
      }
      asm volatile("s_waitcnt lgkmcnt(0)" ::: "memory");  // own Bs writes visible
      __builtin_amdgcn_sched_barrier(0);
      __builtin_amdgcn_s_barrier();
      __builtin_amdgcn_sched_barrier(0);
    } else if (kt == 6) {
      // publish As(7)/gld(7) (issued kt=5; ~1.5kt of cover) before kt=7 reads
      asm volatile("s_waitcnt vmcnt(0)" ::: "memory");
      __builtin_amdgcn_sched_barrier(0);
      __builtin_amdgcn_s_barrier();
      __builtin_amdgcn_sched_barrier(0);
    }
  }
  // epilogue: plain row-major Y f16 store (no bias/relu here — Y is linear)
#pragma unroll
  for (int i = 0; i < 4; ++i) {
    const int u0r = m0 + wm * 64 + i * 16 + quad * 4;
#pragma unroll
    for (int j = 0; j < 4; ++j) {
      const int col = n0 + wn * 64 + j * 16 + lr;
#pragma unroll
      for (int r = 0; r < 4; ++r)
        Y[(size_t)(u0r + r) * Ncol + col] = f2h_bits(acc[i][j][r]);
    }
  }
}

// ---------------------------------------------------------------------------
// K3 (MFMA, fp16, w2-fused): grid (NN) x 4 waves. Per bp: stage Y-slab
// [64t][32c] (4KB, linear, gld_lds) -> 16 MFMAs with w2^T frags ->
// relu(+b2) -> repack f16 into myl ([tc][h], XOR-swizzled) -> TCN phase
// (unchanged) -> FC epilogue (unchanged). Y prefetch issued right after the
// 4 b-frag ds_reads drain; ~2500 cyc of MFMA/VALU cover HBM latency before
// the end-of-iter vmcnt(0).
// ---------------------------------------------------------------------------
__global__ __launch_bounds__(256, 2) void k3_tcn(const u16* __restrict__ Yg,
                                                 const u16* __restrict__ Wb,
                                                 const u16* __restrict__ w2t,
                                                 const float* __restrict__ b2g,
                                                 const float* __restrict__ tbg,
                                                 const float* __restrict__ fwg,
                                                 const float* __restrict__ fbg,
                                                 float* __restrict__ outg,
                                                 int b0, int NcY, int CBcur) {
  __shared__ __align__(16) char wlds[24576];
  __shared__ __align__(16) char ylds_s[4][4096];
  __shared__ __align__(16) char myl_s[4][8192];
  const int tid = threadIdx.x;
  const int n = blockIdx.x;
  const int w = tid >> 6, l = tid & 63;
  const int quad = l >> 4, lr = l & 15;
  const u16* Wp = Wb + (size_t)n * 12288;
#pragma unroll
  for (int c = 0; c < 6; ++c)
    gld_lds16(Wp + (c * 4 + w) * 512 + (size_t)l * 8, wlds + (c * 4 + w) * 1024);
  // w2^T A-fragments (same layout as old k2's wf)
  f16x8 wf[4];
#pragma unroll
  for (int i = 0; i < 4; ++i)
    wf[i] = *(const f16x8*)(w2t + (i * 16 + lr) * 32 + quad * 8);
  float b2v[4][4];
#pragma unroll
  for (int i = 0; i < 4; ++i)
#pragma unroll
    for (int r = 0; r < 4; ++r) b2v[i][r] = b2g[i * 16 + quad * 4 + r];
  float tbv[4][4];
#pragma unroll
  for (int i = 0; i < 4; ++i)
#pragma unroll
    for (int r = 0; r < 4; ++r) tbv[i][r] = tbg[n * 64 + i * 16 + quad * 4 + r];
  f16x2h fwh[16][2];
#pragma unroll
  for (int i = 0; i < 4; ++i)
#pragma unroll
    for (int r = 0; r < 4; ++r) {
      const float* fb = fwg + (i * 16 + quad * 4 + r) * 64 + lr;
      fwh[i * 4 + r][0] = pkh(fb[0], fb[16]);
      fwh[i * 4 + r][1] = pkh(fb[32], fb[48]);
    }
  const float fcb = fbg[0];
  f16x8 bz;
#pragma unroll
  for (int jj = 0; jj < 8; ++jj) bz[jj] = (_Float16)0.f;
  char* yl = ylds_s[w];
  char* myl = myl_s[w];
  if (w < CBcur) {
    const u16* Ys0 = Yg + (size_t)n * NcY + w * 2048;
#pragma unroll
    for (int c = 0; c < 4; ++c)
      gld_lds16(Ys0 + c * 512 + (size_t)l * 8, yl + c * 1024);
  }
  asm volatile("s_waitcnt vmcnt(0)" ::: "memory");
  __syncthreads();
  const int lx7 = lr & 7;
  const f32x4 zz = {0.f, 0.f, 0.f, 0.f};
  for (int bp = w; bp < CBcur; bp += 4) {
    const bool hasNext = (bp + 4) < CBcur;
    // b-fragments from Y-slab: B[t = j*16+lr][c = quad*8..+8]
    f16x8 byf[4];
#pragma unroll
    for (int j = 0; j < 4; ++j)
      byf[j] = *(const f16x8*)(yl + (j * 16 + lr) * 64 + quad * 16);
    asm volatile("s_waitcnt lgkmcnt(0)" ::: "memory");
    __builtin_amdgcn_sched_barrier(0);
    // yl fully consumed into regs -> async prefetch next Y-slab into it
    if (hasNext) {
      const u16* Yn = Yg + (size_t)n * NcY + (bp + 4) * 2048;
#pragma unroll
      for (int c = 0; c < 4; ++c)
        gld_lds16(Yn + c * 512 + (size_t)l * 8, yl + c * 1024);
    }
    // h2 = relu(Y@w2 + b2): D[h = i*16+quad*4+r][t = j*16+lr]
#pragma unroll
    for (int i = 0; i < 4; ++i) {
      const int un = ((i * 2 + (quad >> 1)) ^ lx7) << 4;
#pragma unroll
      for (int j = 0; j < 4; ++j) {
        f32x4 p = __builtin_amdgcn_mfma_f32_16x16x32_f16(wf[i], byf[j], zz, 0, 0, 0);
        const float v0 = fmaxf(p[0] + b2v[i][0], 0.f);
        const float v1 = fmaxf(p[1] + b2v[i][1], 0.f);
        const float v2 = fmaxf(p[2] + b2v[i][2], 0.f);
        const float v3 = fmaxf(p[3] + b2v[i][3], 0.f);
        uint2 st;
        st.x = pk2h(v0, v1);
        st.y = pk2h(v2, v3);
        *(uint2*)(myl + (j * 16 + lr) * 128 + un + ((quad & 1) << 3)) = st;
      }
    }
    asm volatile("s_waitcnt lgkmcnt(0)" ::: "memory");
    __builtin_amdgcn_sched_barrier(0);
    // TCN phase (unchanged): reads wlds (W) + myl (h2 slab)
    f32x4 acc[4][4];
#pragma unroll
    for (int i = 0; i < 4; ++i)
#pragma unroll
      for (int j = 0; j < 4; ++j) acc[i][j] = zz;
#pragma unroll
    for (int ks = 0; ks < 2; ++ks)
#pragma unroll
      for (int kk = 0; kk < 3; ++kk) {
        const int usw = ((ks * 4 + quad) ^ lx7) << 4;
        f16x8 afr[4], bfr[4];
#pragma unroll
        for (int i = 0; i < 4; ++i)
          afr[i] = *(const f16x8*)(wlds + kk * 8192 + (i * 16 + lr) * 128 + usw);
#pragma unroll
        for (int j = 0; j < 4; ++j) {
          const int tau = j * 16 + lr + kk - 1;
          const int tc = min(max(tau, 0), 63);
          const int off = tc * 128 + (((ks * 4 + quad) ^ (tc & 7)) << 4);
          const f16x8 v = *(const f16x8*)(myl + off);
          bfr[j] = (tau == tc) ? v : bz;
        }
#pragma unroll
        for (int i = 0; i < 4; ++i)
#pragma unroll
          for (int j = 0; j < 4; ++j)
            acc[i][j] = __builtin_amdgcn_mfma_f32_16x16x32_f16(afr[i], bfr[j],
                                                               acc[i][j], 0, 0, 0);
      }
    // FC epilogue (pure-register; covers part of the prefetch latency)
    f16x2h pacc;
    pacc[0] = (_Float16)0.f; pacc[1] = (_Float16)0.f;
#pragma unroll
    for (int i = 0; i < 4; ++i)
#pragma unroll
      for (int r = 0; r < 4; ++r) {
        const float v0 = fmaxf(acc[i][0][r] + tbv[i][r], 0.f);
        const float v1 = fmaxf(acc[i][1][r] + tbv[i][r], 0.f);
        const float v2 = fmaxf(acc[i][2][r] + tbv[i][r], 0.f);
        const float v3 = fmaxf(acc[i][3][r] + tbv[i][r], 0.f);
        pacc = pkh(v0, v1) * fwh[i * 4 + r][0] + pacc;
        pacc = pkh(v2, v3) * fwh[i * 4 + r][1] + pacc;
      }
    float s = (float)pacc[0] + (float)pacc[1];
#pragma unroll
    for (int off = 32; off > 0; off >>= 1) s += __shfl_xor(s, off, 64);
    if (l == 0) outg[(size_t)(b0 + bp) * NN + n] = s + fcb;
    // prefetch must land before next iteration's byf reads
    if (hasNext) {
      asm volatile("s_waitcnt vmcnt(0)" ::: "memory");
      __builtin_amdgcn_sched_barrier(0);
    }
  }
}

// ---------------------------------------------------------------------------
extern "C" void kernel_launch(void* const* d_in, const int* in_sizes, int n_in,
                              void* d_out, int out_size, void* d_ws, size_t ws_size,
                              hipStream_t stream) {
  const float* xg   = (const float*)d_in[0];
  const float* adjg = (const float*)d_in[1];
  const float* w1g  = (const float*)d_in[2];
  const float* b1g  = (const float*)d_in[3];
  const float* w2g  = (const float*)d_in[4];
  const float* b2g  = (const float*)d_in[5];
  const float* twg  = (const float*)d_in[6];
  const float* tbg  = (const float*)d_in[7];
  const float* fwg  = (const float*)d_in[8];
  const float* fbg  = (const float*)d_in[9];
  float* outg = (float*)d_out;

  char* ws = (char*)d_ws;
  float* Sg = (float*)ws;                      // 4,194,304 B
  u16* adjb = (u16*)(ws + 4194304);            //   524,288 B
  u16* w2t  = (u16*)(ws + 4718592);            //     8,192 B (4KB used)
  u16* Wb   = (u16*)(ws + 4726784);            // 12,582,912 B
  const size_t fixedB = 17309696;
  int CB = 32;
  while (CB > 1 && fixedB + (size_t)CB * 2097152ull > ws_size) CB >>= 1;
  u16* Yg = (u16*)(ws + fixedB);               // 512 rows x CB*2048 cols, f16
  u16* xh = Yg;  // xh (2MB) overlaps Yg: dead before first k2y write
  const int Ncol = CB * 2048;

  kcvt_adj<<<1024, 256, 0, stream>>>(adjg, adjb);
  kcvt_w2t<<<8, 256, 0, stream>>>(w2g, w2t);
  kcvt_w<<<512, 256, 0, stream>>>(twg, Wb);
  kcvt_x<<<4096, 256, 0, stream>>>(xg, xh);
  k0h<<<dim3(16, 4), 256, 0, stream>>>(xh, adjb, Sg);
  for (int b0 = 0; b0 < BB; b0 += CB) {
    k2y<<<dim3(4, CB * 16), 256, 0, stream>>>(adjb, Sg, w1g, b1g, Yg, Ncol, b0);
    k3_tcn<<<dim3(NN), 256, 0, stream>>>(Yg, Wb, w2t, b2g, tbg, fwg, fbg, outg,
                                         b0, Ncol, CB);
  }
}

// Round 5
// 184.389 us; speedup vs baseline: 1.3952x; 1.0035x over previous
//
#include <hip/hip_runtime.h>
#include <hip/hip_bf16.h>

#define BB 32
#define TT 64
#define NN 512
#define HH 64

using u16 = unsigned short;
using u32 = unsigned int;
typedef _Float16 f16x8 __attribute__((ext_vector_type(8)));
typedef _Float16 f16x2h __attribute__((ext_vector_type(2)));
typedef __fp16 fp16x2 __attribute__((ext_vector_type(2)));
typedef __attribute__((ext_vector_type(4))) float f32x4;

__device__ __forceinline__ u16 f2h_bits(float f) {
  _Float16 h = (_Float16)f;  // v_cvt_f16_f32, RNE, 1 instr
  u16 u; __builtin_memcpy(&u, &h, 2); return u;
}
__device__ __forceinline__ u32 pk2h(float a, float b) {  // v_cvt_pkrtz, 1 instr
  fp16x2 h = __builtin_amdgcn_cvt_pkrtz(a, b);
  u32 u; __builtin_memcpy(&u, &h, 4); return u;
}
__device__ __forceinline__ f16x2h pkh(float a, float b) {  // pkrtz -> _Float16 pair
  fp16x2 h = __builtin_amdgcn_cvt_pkrtz(a, b);
  f16x2h r; __builtin_memcpy(&r, &h, 4); return r;
}

// async global->LDS, 16B per lane; lds base wave-uniform, lane i lands at
// ldsbase + i*16; GLOBAL address is per-lane (must include lane term).
__device__ __forceinline__ void gld_lds16(const void* g, void* l) {
  __builtin_amdgcn_global_load_lds(
      (const __attribute__((address_space(1))) u32*)g,
      (__attribute__((address_space(3))) u32*)l, 16, 0, 0);
}

// ---------------------------------------------------------------------------
// merged elementwise conversions (adj, w2^T, x) — one launch, fp32 -> fp16.
// grid 4096 x 256; thread i handles adj[i] (i<262144), w2t[i] (i<2048),
// x[i] (i<1048576). All coalesced.
// ---------------------------------------------------------------------------
__global__ __launch_bounds__(256) void kcvt_all(const float* __restrict__ a,
                                                u16* __restrict__ oa,
                                                const float* __restrict__ w2,
                                                u16* __restrict__ ow,
                                                const float* __restrict__ x,
                                                u16* __restrict__ ox) {
  const int i = blockIdx.x * 256 + threadIdx.x;
  if (i < 262144) oa[i] = f2h_bits(a[i]);
  if (i < 2048) {
    const int h = i >> 5, c = i & 31;
    ow[i] = f2h_bits(w2[c * 64 + h]);
  }
  ox[i] = f2h_bits(x[i]);  // grid exactly covers 1048576
}

// tcn_w [n][ho][hi][kk] (fp32) -> Wb [n][kk][ho][his] (f16), his = hi with its
// 16B unit XOR-swizzled by (ho&7) (involution). Coalesced read -> LDS scatter
// -> coalesced 16B write. grid (512 n), 256 threads.
__global__ __launch_bounds__(256) void kcvt_w(const float* __restrict__ tw,
                                              u16* __restrict__ o) {
  __shared__ u16 wl[3][64][64];  // [kk][ho][his], 24KB
  const int tid = threadIdx.x;
  const int n = blockIdx.x;
  const float4* pf = (const float4*)(tw + (size_t)n * 12288);
#pragma unroll
  for (int q = 0; q < 12; ++q) {
    const int fi = q * 256 + tid;
    const float4 v = pf[fi];
    const float f[4] = {v.x, v.y, v.z, v.w};
#pragma unroll
    for (int j = 0; j < 4; ++j) {
      const int e = fi * 4 + j;
      const int ho = e / 192;
      const int rem = e - ho * 192;
      const int hi = rem / 3;
      const int kk = rem - hi * 3;
      const int his = (((hi >> 3) ^ (ho & 7)) << 3) | (hi & 7);
      wl[kk][ho][his] = f2h_bits(f[j]);
    }
  }
  __syncthreads();
  const u16* src = &wl[0][0][0];
  u16* dst = o + (size_t)n * 12288;
#pragma unroll
  for (int q = 0; q < 6; ++q) {
    const int u = q * 256 + tid;  // 1536 16B units
    *(uint4*)(dst + u * 8) = *(const uint4*)(src + u * 8);
  }
}

// ---------------------------------------------------------------------------
// K0 (MFMA f16): S[bt][u] = sum_v xh[bt][v] * adjb[u][v], fp32 out.
// 128x128 tile, BK=64, gld_lds w16, XOR LDS. grid (16,4), 256 thr, 2x2 waves.
// ---------------------------------------------------------------------------
__global__ __launch_bounds__(256) void k0h(const u16* __restrict__ A,
                                           const u16* __restrict__ Bm,
                                           float* __restrict__ Sg) {
  __shared__ __align__(16) char smem[32768];  // As 16KB | Bs 16KB
  const int tid = threadIdx.x;
  const int w = tid >> 6, l = tid & 63;
  const int quad = l >> 4, lr = l & 15;
  const int m0 = blockIdx.x * 128, n0 = blockIdx.y * 128;
  const int wm = w >> 1, wn = w & 1;
  const int rB = w * 8 + (l >> 3);
  const int uu = l & 7;
  const u16* agp[4]; const u16* bgp[4];
#pragma unroll
  for (int c = 0; c < 4; ++c) {
    const int r = rB + c * 32;
    agp[c] = A + (size_t)(m0 + r) * 512 + ((uu ^ (r & 7)) * 8);
    bgp[c] = Bm + (size_t)(n0 + r) * 512 + ((uu ^ (r & 7)) * 8);
  }
  char* As = smem;
  char* Bs = smem + 16384;
  int arow[4], brow[4];
#pragma unroll
  for (int i = 0; i < 4; ++i) {
    arow[i] = (wm * 64 + i * 16 + lr) * 128;
    brow[i] = (wn * 64 + i * 16 + lr) * 128;
  }
  const f32x4 zz = {0.f, 0.f, 0.f, 0.f};
  f32x4 acc[4][4];
#pragma unroll
  for (int i = 0; i < 4; ++i)
#pragma unroll
    for (int j = 0; j < 4; ++j) acc[i][j] = zz;
  const int lx7 = lr & 7;
  for (int kt = 0; kt < 8; ++kt) {
#pragma unroll
    for (int c = 0; c < 4; ++c) {
      gld_lds16(agp[c] + kt * 64, As + (c * 32 + w * 8) * 128);
      gld_lds16(bgp[c] + kt * 64, Bs + (c * 32 + w * 8) * 128);
    }
    __syncthreads();
#pragma unroll
    for (int ks = 0; ks < 2; ++ks) {
      const int coff = (((ks * 4 + quad) ^ lx7)) * 16;
      f16x8 afr[4], bfr[4];
#pragma unroll
      for (int i = 0; i < 4; ++i) afr[i] = *(const f16x8*)(As + arow[i] + coff);
#pragma unroll
      for (int j = 0; j < 4; ++j) bfr[j] = *(const f16x8*)(Bs + brow[j] + coff);
#pragma unroll
      for (int i = 0; i < 4; ++i)
#pragma unroll
        for (int j = 0; j < 4; ++j)
          acc[i][j] = __builtin_amdgcn_mfma_f32_16x16x32_f16(afr[i], bfr[j], acc[i][j], 0, 0, 0);
    }
    __syncthreads();
  }
#pragma unroll
  for (int i = 0; i < 4; ++i) {
    const int m0r = m0 + wm * 64 + i * 16 + quad * 4;
#pragma unroll
    for (int j = 0; j < 4; ++j) {
      const int nn = n0 + wn * 64 + j * 16 + lr;
#pragma unroll
      for (int r = 0; r < 4; ++r)
        Sg[(size_t)(m0r + r) * 512 + nn] = acc[i][j][r];
    }
  }
}

// ---------------------------------------------------------------------------
// K2y (R3-proven, reverted from R4's regression): double-buffered
// single-barrier schedule. Y = adj @ h1, h1 = relu(w1[c]*S[bt,v]+b1[c])
// built in-LDS by VALU. Per kt: {issue gld_lds As[nxt]; VALU-build Bs[nxt];
// MFMA on [cur]} -> one __syncthreads. R4's raw-barrier counted-vmcnt variant
// regressed (55.9 -> 67.5 us): T4/T5 are 8-phase/8-wave-gated (m232 quadrant),
// and sched_barrier(0) pinning defeated compiler scheduling (m141).
// LDS 64KB: As0|As1|Bs0|Bs1. grid (4, Ncol/128), 256 thr, 2x2 waves.
// ---------------------------------------------------------------------------
__global__ __launch_bounds__(256) void k2y(
    const u16* __restrict__ A, const float* __restrict__ Sg,
    const float* __restrict__ w1g, const float* __restrict__ b1g,
    u16* __restrict__ Y, int Ncol, int b0) {
  __shared__ __align__(16) char smem[65536];  // As0 16K | As1 16K | Bs0 16K | Bs1 16K
  const int tid = threadIdx.x;
  const int w = tid >> 6, l = tid & 63;
  const int quad = l >> 4, lr = l & 15;
  const int m0 = blockIdx.x * 128, n0 = blockIdx.y * 128;
  const int wm = w >> 1, wn = w & 1;
  const int rB = w * 8 + (l >> 3);
  const int uu = l & 7;
  const u16* agp[4];
#pragma unroll
  for (int c = 0; c < 4; ++c) {
    const int r = rB + c * 32;
    agp[c] = A + (size_t)(m0 + r) * 512 + ((uu ^ (r & 7)) * 8);
  }
  // panel-build lane constants
  const int oct = l & 7;   // v-octet (8 f16 along v)
  const int crow = l >> 3; // c base 0..7; c = crow + 8k
  const int swzW = (oct ^ crow) << 4;  // (row&7)==crow for all k
  float w1c[4], b1c[4];
#pragma unroll
  for (int k = 0; k < 4; ++k) {
    w1c[k] = w1g[crow + 8 * k];
    b1c[k] = b1g[crow + 8 * k];
  }
  // S row for this wave's bt: bt_local = tn*4 + w
  const float* sb = Sg + ((size_t)(b0 * 64) + (size_t)blockIdx.y * 4 + w) * 512;
  int arow[4], brow[4];
#pragma unroll
  for (int i = 0; i < 4; ++i) {
    arow[i] = (wm * 64 + i * 16 + lr) * 128;
    brow[i] = (wn * 64 + i * 16 + lr) * 128;
  }
  const f32x4 zz = {0.f, 0.f, 0.f, 0.f};
  f32x4 acc[4][4];
#pragma unroll
  for (int i = 0; i < 4; ++i)
#pragma unroll
    for (int j = 0; j < 4; ++j) acc[i][j] = zz;
  const int lx7 = lr & 7;
  const int prow = w * 32 + crow;  // panel row base for this lane

  // ---- prologue: stage As0, build Bs0 from S(0), issue S(1) loads ----
  float4 svA = *(const float4*)(sb + oct * 8);
  float4 svB = *(const float4*)(sb + oct * 8 + 4);
#pragma unroll
  for (int c = 0; c < 4; ++c)
    gld_lds16(agp[c], smem + (c * 32 + w * 8) * 128);
#pragma unroll
  for (int k = 0; k < 4; ++k) {
    const float a = w1c[k], b = b1c[k];
    uint4 st;
    st.x = pk2h(fmaxf(a * svA.x + b, 0.f), fmaxf(a * svA.y + b, 0.f));
    st.y = pk2h(fmaxf(a * svA.z + b, 0.f), fmaxf(a * svA.w + b, 0.f));
    st.z = pk2h(fmaxf(a * svB.x + b, 0.f), fmaxf(a * svB.y + b, 0.f));
    st.w = pk2h(fmaxf(a * svB.z + b, 0.f), fmaxf(a * svB.w + b, 0.f));
    *(uint4*)(smem + 32768 + (prow + 8 * k) * 128 + swzW) = st;
  }
  svA = *(const float4*)(sb + 64 + oct * 8);
  svB = *(const float4*)(sb + 64 + oct * 8 + 4);
  __syncthreads();

  // ---- main loop: one barrier per kt ----
  for (int kt = 0; kt < 8; ++kt) {
    const int cur = kt & 1, nxt = cur ^ 1;
    char* Asc = smem + cur * 16384;
    char* Bsc = smem + 32768 + cur * 16384;
    if (kt < 7) {
      char* Asn = smem + nxt * 16384;
      char* Bsn = smem + 32768 + nxt * 16384;
#pragma unroll
      for (int c = 0; c < 4; ++c)
        gld_lds16(agp[c] + (kt + 1) * 64, Asn + (c * 32 + w * 8) * 128);
      // build panel(kt+1) from sv (= S(kt+1))
#pragma unroll
      for (int k = 0; k < 4; ++k) {
        const float a = w1c[k], b = b1c[k];
        uint4 st;
        st.x = pk2h(fmaxf(a * svA.x + b, 0.f), fmaxf(a * svA.y + b, 0.f));
        st.y = pk2h(fmaxf(a * svA.z + b, 0.f), fmaxf(a * svA.w + b, 0.f));
        st.z = pk2h(fmaxf(a * svB.x + b, 0.f), fmaxf(a * svB.y + b, 0.f));
        st.w = pk2h(fmaxf(a * svB.z + b, 0.f), fmaxf(a * svB.w + b, 0.f));
        *(uint4*)(Bsn + (prow + 8 * k) * 128 + swzW) = st;
      }
      if (kt < 6) {  // issue S(kt+2) loads (consumed next iter)
        svA = *(const float4*)(sb + (kt + 2) * 64 + oct * 8);
        svB = *(const float4*)(sb + (kt + 2) * 64 + oct * 8 + 4);
      }
    }
    // MFMA phase on [cur]
#pragma unroll
    for (int ks = 0; ks < 2; ++ks) {
      const int coff = (((ks * 4 + quad) ^ lx7)) * 16;
      f16x8 afr[4], bfr[4];
#pragma unroll
      for (int i = 0; i < 4; ++i) afr[i] = *(const f16x8*)(Asc + arow[i] + coff);
#pragma unroll
      for (int j = 0; j < 4; ++j) bfr[j] = *(const f16x8*)(Bsc + brow[j] + coff);
#pragma unroll
      for (int i = 0; i < 4; ++i)
#pragma unroll
        for (int j = 0; j < 4; ++j)
          acc[i][j] = __builtin_amdgcn_mfma_f32_16x16x32_f16(afr[i], bfr[j], acc[i][j], 0, 0, 0);
    }
    if (kt < 7) __syncthreads();
  }
  // epilogue: plain row-major Y f16 store (no bias/relu here — Y is linear)
#pragma unroll
  for (int i = 0; i < 4; ++i) {
    const int u0r = m0 + wm * 64 + i * 16 + quad * 4;
#pragma unroll
    for (int j = 0; j < 4; ++j) {
      const int col = n0 + wn * 64 + j * 16 + lr;
#pragma unroll
      for (int r = 0; r < 4; ++r)
        Y[(size_t)(u0r + r) * Ncol + col] = f2h_bits(acc[i][j][r]);
    }
  }
}

// ---------------------------------------------------------------------------
// K3 (MFMA, fp16, w2-fused, R5: halo-padded h2 slab): grid (NN) x 4 waves.
// Per bp: stage Y-slab [64t][32c] (4KB, linear, gld_lds) -> 16 MFMAs with
// w2^T frags -> relu(+b2) -> repack f16 into myl rows 1..64 (row = t+1,
// XOR-swizzled within row) -> TCN phase reads row (t+kk) DIRECTLY: halo rows
// 0 and 65 are permanently zero, eliminating the per-fragment clamp +
// cndmask-select chain (~190 VALU/iter/wave on the serial LDS->MFMA path)
// -> FC epilogue. LDS 74.8KB/block, 2 blocks/CU.
// ---------------------------------------------------------------------------
__global__ __launch_bounds__(256, 2) void k3_tcn(const u16* __restrict__ Yg,
                                                 const u16* __restrict__ Wb,
                                                 const u16* __restrict__ w2t,
                                                 const float* __restrict__ b2g,
                                                 const float* __restrict__ tbg,
                                                 const float* __restrict__ fwg,
                                                 const float* __restrict__ fbg,
                                                 float* __restrict__ outg,
                                                 int b0, int NcY, int CBcur) {
  __shared__ __align__(16) char wlds[24576];
  __shared__ __align__(16) char ylds_s[4][4096];
  __shared__ __align__(16) char myl_s[4][8448];  // 66 rows x 128B (halo 0,65)
  const int tid = threadIdx.x;
  const int n = blockIdx.x;
  const int w = tid >> 6, l = tid & 63;
  const int quad = l >> 4, lr = l & 15;
  const u16* Wp = Wb + (size_t)n * 12288;
#pragma unroll
  for (int c = 0; c < 6; ++c)
    gld_lds16(Wp + (c * 4 + w) * 512 + (size_t)l * 8, wlds + (c * 4 + w) * 1024);
  // w2^T A-fragments
  f16x8 wf[4];
#pragma unroll
  for (int i = 0; i < 4; ++i)
    wf[i] = *(const f16x8*)(w2t + (i * 16 + lr) * 32 + quad * 8);
  float b2v[4][4];
#pragma unroll
  for (int i = 0; i < 4; ++i)
#pragma unroll
    for (int r = 0; r < 4; ++r) b2v[i][r] = b2g[i * 16 + quad * 4 + r];
  float tbv[4][4];
#pragma unroll
  for (int i = 0; i < 4; ++i)
#pragma unroll
    for (int r = 0; r < 4; ++r) tbv[i][r] = tbg[n * 64 + i * 16 + quad * 4 + r];
  f16x2h fwh[16][2];
#pragma unroll
  for (int i = 0; i < 4; ++i)
#pragma unroll
    for (int r = 0; r < 4; ++r) {
      const float* fb = fwg + (i * 16 + quad * 4 + r) * 64 + lr;
      fwh[i * 4 + r][0] = pkh(fb[0], fb[16]);
      fwh[i * 4 + r][1] = pkh(fb[32], fb[48]);
    }
  const float fcb = fbg[0];
  char* yl = ylds_s[w];
  char* myl = myl_s[w];
  // zero the halo rows (0 and 65) once; swizzle is a within-row permutation,
  // so zeroing the full 128B row is layout-independent. Rows 1..64 are
  // rewritten every bp; halo stays zero.
  if (l < 8) {
    const uint4 z4 = {0u, 0u, 0u, 0u};
    *(uint4*)(myl + l * 16) = z4;
    *(uint4*)(myl + 65 * 128 + l * 16) = z4;
  }
  if (w < CBcur) {
    const u16* Ys0 = Yg + (size_t)n * NcY + w * 2048;
#pragma unroll
    for (int c = 0; c < 4; ++c)
      gld_lds16(Ys0 + c * 512 + (size_t)l * 8, yl + c * 1024);
  }
  asm volatile("s_waitcnt vmcnt(0)" ::: "memory");
  __syncthreads();
  const int lx7 = lr & 7;
  const int lx7p = (lr + 1) & 7;  // write-row (t+1) & 7
  const f32x4 zz = {0.f, 0.f, 0.f, 0.f};
  for (int bp = w; bp < CBcur; bp += 4) {
    const bool hasNext = (bp + 4) < CBcur;
    // b-fragments from Y-slab: B[t = j*16+lr][c = quad*8..+8]
    f16x8 byf[4];
#pragma unroll
    for (int j = 0; j < 4; ++j)
      byf[j] = *(const f16x8*)(yl + (j * 16 + lr) * 64 + quad * 16);
    asm volatile("s_waitcnt lgkmcnt(0)" ::: "memory");
    __builtin_amdgcn_sched_barrier(0);
    // yl fully consumed into regs -> async prefetch next Y-slab into it
    if (hasNext) {
      const u16* Yn = Yg + (size_t)n * NcY + (bp + 4) * 2048;
#pragma unroll
      for (int c = 0; c < 4; ++c)
        gld_lds16(Yn + c * 512 + (size_t)l * 8, yl + c * 1024);
    }
    // h2 = relu(Y@w2 + b2): D[h = i*16+quad*4+r][t = j*16+lr] -> row t+1
#pragma unroll
    for (int i = 0; i < 4; ++i) {
      const int un = ((i * 2 + (quad >> 1)) ^ lx7p) << 4;
#pragma unroll
      for (int j = 0; j < 4; ++j) {
        f32x4 p = __builtin_amdgcn_mfma_f32_16x16x32_f16(wf[i], byf[j], zz, 0, 0, 0);
        const float v0 = fmaxf(p[0] + b2v[i][0], 0.f);
        const float v1 = fmaxf(p[1] + b2v[i][1], 0.f);
        const float v2 = fmaxf(p[2] + b2v[i][2], 0.f);
        const float v3 = fmaxf(p[3] + b2v[i][3], 0.f);
        uint2 st;
        st.x = pk2h(v0, v1);
        st.y = pk2h(v2, v3);
        *(uint2*)(myl + (j * 16 + lr + 1) * 128 + un + ((quad & 1) << 3)) = st;
      }
    }
    asm volatile("s_waitcnt lgkmcnt(0)" ::: "memory");
    __builtin_amdgcn_sched_barrier(0);
    // TCN phase: reads wlds (W) + myl rows (t+kk) directly (halo-safe)
    f32x4 acc[4][4];
#pragma unroll
    for (int i = 0; i < 4; ++i)
#pragma unroll
      for (int j = 0; j < 4; ++j) acc[i][j] = zz;
#pragma unroll
    for (int ks = 0; ks < 2; ++ks)
#pragma unroll
      for (int kk = 0; kk < 3; ++kk) {
        const int usw = ((ks * 4 + quad) ^ lx7) << 4;
        const int rx7 = (lr + kk) & 7;  // read-row & 7 (j*16 invisible to &7)
        const int rsw = ((ks * 4 + quad) ^ rx7) << 4;
        f16x8 afr[4], bfr[4];
#pragma unroll
        for (int i = 0; i < 4; ++i)
          afr[i] = *(const f16x8*)(wlds + kk * 8192 + (i * 16 + lr) * 128 + usw);
#pragma unroll
        for (int j = 0; j < 4; ++j)
          bfr[j] = *(const f16x8*)(myl + (j * 16 + lr + kk) * 128 + rsw);
#pragma unroll
        for (int i = 0; i < 4; ++i)
#pragma unroll
          for (int j = 0; j < 4; ++j)
            acc[i][j] = __builtin_amdgcn_mfma_f32_16x16x32_f16(afr[i], bfr[j],
                                                               acc[i][j], 0, 0, 0);
      }
    // FC epilogue (pure-register; covers part of the prefetch latency)
    f16x2h pacc;
    pacc[0] = (_Float16)0.f; pacc[1] = (_Float16)0.f;
#pragma unroll
    for (int i = 0; i < 4; ++i)
#pragma unroll
      for (int r = 0; r < 4; ++r) {
        const float v0 = fmaxf(acc[i][0][r] + tbv[i][r], 0.f);
        const float v1 = fmaxf(acc[i][1][r] + tbv[i][r], 0.f);
        const float v2 = fmaxf(acc[i][2][r] + tbv[i][r], 0.f);
        const float v3 = fmaxf(acc[i][3][r] + tbv[i][r], 0.f);
        pacc = pkh(v0, v1) * fwh[i * 4 + r][0] + pacc;
        pacc = pkh(v2, v3) * fwh[i * 4 + r][1] + pacc;
      }
    float s = (float)pacc[0] + (float)pacc[1];
#pragma unroll
    for (int off = 32; off > 0; off >>= 1) s += __shfl_xor(s, off, 64);
    if (l == 0) outg[(size_t)(b0 + bp) * NN + n] = s + fcb;
    // prefetch must land before next iteration's byf reads
    if (hasNext) {
      asm volatile("s_waitcnt vmcnt(0)" ::: "memory");
      __builtin_amdgcn_sched_barrier(0);
    }
  }
}

// ---------------------------------------------------------------------------
extern "C" void kernel_launch(void* const* d_in, const int* in_sizes, int n_in,
                              void* d_out, int out_size, void* d_ws, size_t ws_size,
                              hipStream_t stream) {
  const float* xg   = (const float*)d_in[0];
  const float* adjg = (const float*)d_in[1];
  const float* w1g  = (const float*)d_in[2];
  const float* b1g  = (const float*)d_in[3];
  const float* w2g  = (const float*)d_in[4];
  const float* b2g  = (const float*)d_in[5];
  const float* twg  = (const float*)d_in[6];
  const float* tbg  = (const float*)d_in[7];
  const float* fwg  = (const float*)d_in[8];
  const float* fbg  = (const float*)d_in[9];
  float* outg = (float*)d_out;

  char* ws = (char*)d_ws;
  float* Sg = (float*)ws;                      // 4,194,304 B
  u16* adjb = (u16*)(ws + 4194304);            //   524,288 B
  u16* w2t  = (u16*)(ws + 4718592);            //     8,192 B (4KB used)
  u16* Wb   = (u16*)(ws + 4726784);            // 12,582,912 B
  const size_t fixedB = 17309696;
  int CB = 32;
  while (CB > 1 && fixedB + (size_t)CB * 2097152ull > ws_size) CB >>= 1;
  u16* Yg = (u16*)(ws + fixedB);               // 512 rows x CB*2048 cols, f16
  u16* xh = Yg;  // xh (2MB) overlaps Yg: dead before first k2y write
  const int Ncol = CB * 2048;

  kcvt_all<<<4096, 256, 0, stream>>>(adjg, adjb, w2g, w2t, xg, xh);
  kcvt_w<<<512, 256, 0, stream>>>(twg, Wb);
  k0h<<<dim3(16, 4), 256, 0, stream>>>(xh, adjb, Sg);
  for (int b0 = 0; b0 < BB; b0 += CB) {
    k2y<<<dim3(4, CB * 16), 256, 0, stream>>>(adjb, Sg, w1g, b1g, Yg, Ncol, b0);
    k3_tcn<<<dim3(NN), 256, 0, stream>>>(Yg, Wb, w2t, b2g, tbg, fwg, fbg, outg,
                                         b0, Ncol, CB);
  }
}

// Round 8
// 176.688 us; speedup vs baseline: 1.4560x; 1.0436x over previous
//
#include <hip/hip_runtime.h>
#include <hip/hip_bf16.h>

#define BB 32
#define TT 64
#define NN 512
#define HH 64

using u16 = unsigned short;
using u32 = unsigned int;
typedef _Float16 f16x8 __attribute__((ext_vector_type(8)));
typedef _Float16 f16x2h __attribute__((ext_vector_type(2)));
typedef __fp16 fp16x2 __attribute__((ext_vector_type(2)));
typedef __attribute__((ext_vector_type(4))) float f32x4;

__device__ __forceinline__ u16 f2h_bits(float f) {
  _Float16 h = (_Float16)f;  // v_cvt_f16_f32, RNE, 1 instr
  u16 u; __builtin_memcpy(&u, &h, 2); return u;
}
__device__ __forceinline__ u32 pk2h(float a, float b) {  // v_cvt_pkrtz, 1 instr
  fp16x2 h = __builtin_amdgcn_cvt_pkrtz(a, b);
  u32 u; __builtin_memcpy(&u, &h, 4); return u;
}
__device__ __forceinline__ f16x2h pkh(float a, float b) {  // pkrtz -> _Float16 pair
  fp16x2 h = __builtin_amdgcn_cvt_pkrtz(a, b);
  f16x2h r; __builtin_memcpy(&r, &h, 4); return r;
}

// async global->LDS, 16B per lane; lds base wave-uniform, lane i lands at
// ldsbase + i*16; GLOBAL address is per-lane (must include lane term).
__device__ __forceinline__ void gld_lds16(const void* g, void* l) {
  __builtin_amdgcn_global_load_lds(
      (const __attribute__((address_space(1))) u32*)g,
      (__attribute__((address_space(3))) u32*)l, 16, 0, 0);
}

// ---------------------------------------------------------------------------
// merged elementwise conversions (adj, w2^T, x) — one launch, fp32 -> fp16.
// grid 4096 x 256 (R5-proven form).
// ---------------------------------------------------------------------------
__global__ __launch_bounds__(256) void kcvt_all(const float* __restrict__ a,
                                                u16* __restrict__ oa,
                                                const float* __restrict__ w2,
                                                u16* __restrict__ ow,
                                                const float* __restrict__ x,
                                                u16* __restrict__ ox) {
  const int i = blockIdx.x * 256 + threadIdx.x;
  if (i < 262144) oa[i] = f2h_bits(a[i]);
  if (i < 2048) {
    const int h = i >> 5, c = i & 31;
    ow[i] = f2h_bits(w2[c * 64 + h]);
  }
  ox[i] = f2h_bits(x[i]);  // grid exactly covers 1048576
}

// tcn_w [n][ho][hi][kk] (fp32) -> Wb [n][kk][ho][his] (f16), his = hi with its
// 16B unit XOR-swizzled by (ho&7) (involution). Coalesced read -> LDS scatter
// -> coalesced 16B write. grid (512 n), 256 threads. (R5-proven form.)
__global__ __launch_bounds__(256) void kcvt_w(const float* __restrict__ tw,
                                              u16* __restrict__ o) {
  __shared__ u16 wl[3][64][64];  // [kk][ho][his], 24KB
  const int tid = threadIdx.x;
  const int n = blockIdx.x;
  const float4* pf = (const float4*)(tw + (size_t)n * 12288);
#pragma unroll
  for (int q = 0; q < 12; ++q) {
    const int fi = q * 256 + tid;
    const float4 v = pf[fi];
    const float f[4] = {v.x, v.y, v.z, v.w};
#pragma unroll
    for (int j = 0; j < 4; ++j) {
      const int e = fi * 4 + j;
      const int ho = e / 192;
      const int rem = e - ho * 192;
      const int hi = rem / 3;
      const int kk = rem - hi * 3;
      const int his = (((hi >> 3) ^ (ho & 7)) << 3) | (hi & 7);
      wl[kk][ho][his] = f2h_bits(f[j]);
    }
  }
  __syncthreads();
  const u16* src = &wl[0][0][0];
  u16* dst = o + (size_t)n * 12288;
#pragma unroll
  for (int q = 0; q < 6; ++q) {
    const int u = q * 256 + tid;  // 1536 16B units
    *(uint4*)(dst + u * 8) = *(const uint4*)(src + u * 8);
  }
}

// ---------------------------------------------------------------------------
// K0 (MFMA f16, 64x64 tiles for full CU spread): S[bt][u] =
// sum_v xh[bt][v] * adjb[u][v], fp32 out. grid (32,8) = 256 blocks (was 64
// = 25% of CUs -> latency-bound). Same staging/swizzle/fragment pattern as
// the proven 128^2 version, scaled: 2 row-chunks, acc[2][2], 16KB LDS.
// ---------------------------------------------------------------------------
__global__ __launch_bounds__(256) void k0h(const u16* __restrict__ A,
                                           const u16* __restrict__ Bm,
                                           float* __restrict__ Sg) {
  __shared__ __align__(16) char smem[16384];  // As 8KB | Bs 8KB
  const int tid = threadIdx.x;
  const int w = tid >> 6, l = tid & 63;
  const int quad = l >> 4, lr = l & 15;
  const int m0 = blockIdx.x * 64, n0 = blockIdx.y * 64;
  const int wm = w >> 1, wn = w & 1;
  const int rB = w * 8 + (l >> 3);  // 0..31
  const int uu = l & 7;
  const u16* agp[2]; const u16* bgp[2];
#pragma unroll
  for (int c = 0; c < 2; ++c) {
    const int r = rB + c * 32;
    agp[c] = A + (size_t)(m0 + r) * 512 + ((uu ^ (r & 7)) * 8);
    bgp[c] = Bm + (size_t)(n0 + r) * 512 + ((uu ^ (r & 7)) * 8);
  }
  char* As = smem;
  char* Bs = smem + 8192;
  int arow[2], brow[2];
#pragma unroll
  for (int i = 0; i < 2; ++i) {
    arow[i] = (wm * 32 + i * 16 + lr) * 128;
    brow[i] = (wn * 32 + i * 16 + lr) * 128;
  }
  const f32x4 zz = {0.f, 0.f, 0.f, 0.f};
  f32x4 acc[2][2];
#pragma unroll
  for (int i = 0; i < 2; ++i)
#pragma unroll
    for (int j = 0; j < 2; ++j) acc[i][j] = zz;
  const int lx7 = lr & 7;
  for (int kt = 0; kt < 8; ++kt) {
#pragma unroll
    for (int c = 0; c < 2; ++c) {
      gld_lds16(agp[c] + kt * 64, As + (c * 32 + w * 8) * 128);
      gld_lds16(bgp[c] + kt * 64, Bs + (c * 32 + w * 8) * 128);
    }
    __syncthreads();
#pragma unroll
    for (int ks = 0; ks < 2; ++ks) {
      const int coff = (((ks * 4 + quad) ^ lx7)) * 16;
      f16x8 afr[2], bfr[2];
#pragma unroll
      for (int i = 0; i < 2; ++i) afr[i] = *(const f16x8*)(As + arow[i] + coff);
#pragma unroll
      for (int j = 0; j < 2; ++j) bfr[j] = *(const f16x8*)(Bs + brow[j] + coff);
#pragma unroll
      for (int i = 0; i < 2; ++i)
#pragma unroll
        for (int j = 0; j < 2; ++j)
          acc[i][j] = __builtin_amdgcn_mfma_f32_16x16x32_f16(afr[i], bfr[j], acc[i][j], 0, 0, 0);
    }
    __syncthreads();
  }
#pragma unroll
  for (int i = 0; i < 2; ++i) {
    const int m0r = m0 + wm * 32 + i * 16 + quad * 4;
#pragma unroll
    for (int j = 0; j < 2; ++j) {
      const int nn = n0 + wn * 32 + j * 16 + lr;
#pragma unroll
      for (int r = 0; r < 4; ++r)
        Sg[(size_t)(m0r + r) * 512 + nn] = acc[i][j][r];
    }
  }
}

// ---------------------------------------------------------------------------
// K2y (R3-proven): double-buffered single-barrier schedule. Y = adj @ h1,
// h1 = relu(w1[c]*S[bt,v]+b1[c]) built in-LDS by VALU. Per kt: {issue
// gld_lds As[nxt]; VALU-build Bs[nxt]; MFMA on [cur]} -> one __syncthreads.
// LDS 64KB: As0|As1|Bs0|Bs1. grid (4, Ncol/128), 256 thr, 2x2 waves.
// ---------------------------------------------------------------------------
__global__ __launch_bounds__(256) void k2y(
    const u16* __restrict__ A, const float* __restrict__ Sg,
    const float* __restrict__ w1g, const float* __restrict__ b1g,
    u16* __restrict__ Y, int Ncol, int b0) {
  __shared__ __align__(16) char smem[65536];  // As0 16K | As1 16K | Bs0 16K | Bs1 16K
  const int tid = threadIdx.x;
  const int w = tid >> 6, l = tid & 63;
  const int quad = l >> 4, lr = l & 15;
  const int m0 = blockIdx.x * 128, n0 = blockIdx.y * 128;
  const int wm = w >> 1, wn = w & 1;
  const int rB = w * 8 + (l >> 3);
  const int uu = l & 7;
  const u16* agp[4];
#pragma unroll
  for (int c = 0; c < 4; ++c) {
    const int r = rB + c * 32;
    agp[c] = A + (size_t)(m0 + r) * 512 + ((uu ^ (r & 7)) * 8);
  }
  // panel-build lane constants
  const int oct = l & 7;   // v-octet (8 f16 along v)
  const int crow = l >> 3; // c base 0..7; c = crow + 8k
  const int swzW = (oct ^ crow) << 4;  // (row&7)==crow for all k
  float w1c[4], b1c[4];
#pragma unroll
  for (int k = 0; k < 4; ++k) {
    w1c[k] = w1g[crow + 8 * k];
    b1c[k] = b1g[crow + 8 * k];
  }
  // S row for this wave's bt: bt_local = tn*4 + w
  const float* sb = Sg + ((size_t)(b0 * 64) + (size_t)blockIdx.y * 4 + w) * 512;
  int arow[4], brow[4];
#pragma unroll
  for (int i = 0; i < 4; ++i) {
    arow[i] = (wm * 64 + i * 16 + lr) * 128;
    brow[i] = (wn * 64 + i * 16 + lr) * 128;
  }
  const f32x4 zz = {0.f, 0.f, 0.f, 0.f};
  f32x4 acc[4][4];
#pragma unroll
  for (int i = 0; i < 4; ++i)
#pragma unroll
    for (int j = 0; j < 4; ++j) acc[i][j] = zz;
  const int lx7 = lr & 7;
  const int prow = w * 32 + crow;  // panel row base for this lane

  // ---- prologue: stage As0, build Bs0 from S(0), issue S(1) loads ----
  float4 svA = *(const float4*)(sb + oct * 8);
  float4 svB = *(const float4*)(sb + oct * 8 + 4);
#pragma unroll
  for (int c = 0; c < 4; ++c)
    gld_lds16(agp[c], smem + (c * 32 + w * 8) * 128);
#pragma unroll
  for (int k = 0; k < 4; ++k) {
    const float a = w1c[k], b = b1c[k];
    uint4 st;
    st.x = pk2h(fmaxf(a * svA.x + b, 0.f), fmaxf(a * svA.y + b, 0.f));
    st.y = pk2h(fmaxf(a * svA.z + b, 0.f), fmaxf(a * svA.w + b, 0.f));
    st.z = pk2h(fmaxf(a * svB.x + b, 0.f), fmaxf(a * svB.y + b, 0.f));
    st.w = pk2h(fmaxf(a * svB.z + b, 0.f), fmaxf(a * svB.w + b, 0.f));
    *(uint4*)(smem + 32768 + (prow + 8 * k) * 128 + swzW) = st;
  }
  svA = *(const float4*)(sb + 64 + oct * 8);
  svB = *(const float4*)(sb + 64 + oct * 8 + 4);
  __syncthreads();

  // ---- main loop: one barrier per kt ----
  for (int kt = 0; kt < 8; ++kt) {
    const int cur = kt & 1, nxt = cur ^ 1;
    char* Asc = smem + cur * 16384;
    char* Bsc = smem + 32768 + cur * 16384;
    if (kt < 7) {
      char* Asn = smem + nxt * 16384;
      char* Bsn = smem + 32768 + nxt * 16384;
#pragma unroll
      for (int c = 0; c < 4; ++c)
        gld_lds16(agp[c] + (kt + 1) * 64, Asn + (c * 32 + w * 8) * 128);
      // build panel(kt+1) from sv (= S(kt+1))
#pragma unroll
      for (int k = 0; k < 4; ++k) {
        const float a = w1c[k], b = b1c[k];
        uint4 st;
        st.x = pk2h(fmaxf(a * svA.x + b, 0.f), fmaxf(a * svA.y + b, 0.f));
        st.y = pk2h(fmaxf(a * svA.z + b, 0.f), fmaxf(a * svA.w + b, 0.f));
        st.z = pk2h(fmaxf(a * svB.x + b, 0.f), fmaxf(a * svB.y + b, 0.f));
        st.w = pk2h(fmaxf(a * svB.z + b, 0.f), fmaxf(a * svB.w + b, 0.f));
        *(uint4*)(Bsn + (prow + 8 * k) * 128 + swzW) = st;
      }
      if (kt < 6) {  // issue S(kt+2) loads (consumed next iter)
        svA = *(const float4*)(sb + (kt + 2) * 64 + oct * 8);
        svB = *(const float4*)(sb + (kt + 2) * 64 + oct * 8 + 4);
      }
    }
    // MFMA phase on [cur]
#pragma unroll
    for (int ks = 0; ks < 2; ++ks) {
      const int coff = (((ks * 4 + quad) ^ lx7)) * 16;
      f16x8 afr[4], bfr[4];
#pragma unroll
      for (int i = 0; i < 4; ++i) afr[i] = *(const f16x8*)(Asc + arow[i] + coff);
#pragma unroll
      for (int j = 0; j < 4; ++j) bfr[j] = *(const f16x8*)(Bsc + brow[j] + coff);
#pragma unroll
      for (int i = 0; i < 4; ++i)
#pragma unroll
        for (int j = 0; j < 4; ++j)
          acc[i][j] = __builtin_amdgcn_mfma_f32_16x16x32_f16(afr[i], bfr[j], acc[i][j], 0, 0, 0);
    }
    if (kt < 7) __syncthreads();
  }
  // epilogue: plain row-major Y f16 store (no bias/relu here — Y is linear)
#pragma unroll
  for (int i = 0; i < 4; ++i) {
    const int u0r = m0 + wm * 64 + i * 16 + quad * 4;
#pragma unroll
    for (int j = 0; j < 4; ++j) {
      const int col = n0 + wn * 64 + j * 16 + lr;
#pragma unroll
      for (int r = 0; r < 4; ++r)
        Y[(size_t)(u0r + r) * Ncol + col] = f2h_bits(acc[i][j][r]);
    }
  }
}

// ---------------------------------------------------------------------------
// K3 (MFMA, fp16, w2-fused, halo-padded h2 slab): grid (NN) x 4 waves.
// Per bp: stage Y-slab [64t][32c] (4KB, linear, gld_lds) -> 16 MFMAs with
// w2^T frags -> relu(+b2) -> repack f16 into myl rows 1..64 (row = t+1,
// XOR-swizzled within row) -> TCN phase reads row (t+kk) directly (halo rows
// 0 and 65 permanently zero; no clamp/select chain) -> FC epilogue.
// LDS 74.8KB/block, 2 blocks/CU.
// ---------------------------------------------------------------------------
__global__ __launch_bounds__(256, 2) void k3_tcn(const u16* __restrict__ Yg,
                                                 const u16* __restrict__ Wb,
                                                 const u16* __restrict__ w2t,
                                                 const float* __restrict__ b2g,
                                                 const float* __restrict__ tbg,
                                                 const float* __restrict__ fwg,
                                                 const float* __restrict__ fbg,
                                                 float* __restrict__ outg,
                                                 int b0, int NcY, int CBcur) {
  __shared__ __align__(16) char wlds[24576];
  __shared__ __align__(16) char ylds_s[4][4096];
  __shared__ __align__(16) char myl_s[4][8448];  // 66 rows x 128B (halo 0,65)
  const int tid = threadIdx.x;
  const int n = blockIdx.x;
  const int w = tid >> 6, l = tid & 63;
  const int quad = l >> 4, lr = l & 15;
  const u16* Wp = Wb + (size_t)n * 12288;
#pragma unroll
  for (int c = 0; c < 6; ++c)
    gld_lds16(Wp + (c * 4 + w) * 512 + (size_t)l * 8, wlds + (c * 4 + w) * 1024);
  // w2^T A-fragments
  f16x8 wf[4];
#pragma unroll
  for (int i = 0; i < 4; ++i)
    wf[i] = *(const f16x8*)(w2t + (i * 16 + lr) * 32 + quad * 8);
  float b2v[4][4];
#pragma unroll
  for (int i = 0; i < 4; ++i)
#pragma unroll
    for (int r = 0; r < 4; ++r) b2v[i][r] = b2g[i * 16 + quad * 4 + r];
  float tbv[4][4];
#pragma unroll
  for (int i = 0; i < 4; ++i)
#pragma unroll
    for (int r = 0; r < 4; ++r) tbv[i][r] = tbg[n * 64 + i * 16 + quad * 4 + r];
  f16x2h fwh[16][2];
#pragma unroll
  for (int i = 0; i < 4; ++i)
#pragma unroll
    for (int r = 0; r < 4; ++r) {
      const float* fb = fwg + (i * 16 + quad * 4 + r) * 64 + lr;
      fwh[i * 4 + r][0] = pkh(fb[0], fb[16]);
      fwh[i * 4 + r][1] = pkh(fb[32], fb[48]);
    }
  const float fcb = fbg[0];
  char* yl = ylds_s[w];
  char* myl = myl_s[w];
  // zero the halo rows (0 and 65) once; swizzle is a within-row permutation,
  // so zeroing the full 128B row is layout-independent.
  if (l < 8) {
    const uint4 z4 = {0u, 0u, 0u, 0u};
    *(uint4*)(myl + l * 16) = z4;
    *(uint4*)(myl + 65 * 128 + l * 16) = z4;
  }
  if (w < CBcur) {
    const u16* Ys0 = Yg + (size_t)n * NcY + w * 2048;
#pragma unroll
    for (int c = 0; c < 4; ++c)
      gld_lds16(Ys0 + c * 512 + (size_t)l * 8, yl + c * 1024);
  }
  asm volatile("s_waitcnt vmcnt(0)" ::: "memory");
  __syncthreads();
  const int lx7 = lr & 7;
  const int lx7p = (lr + 1) & 7;  // write-row (t+1) & 7
  const f32x4 zz = {0.f, 0.f, 0.f, 0.f};
  for (int bp = w; bp < CBcur; bp += 4) {
    const bool hasNext = (bp + 4) < CBcur;
    // b-fragments from Y-slab: B[t = j*16+lr][c = quad*8..+8]
    f16x8 byf[4];
#pragma unroll
    for (int j = 0; j < 4; ++j)
      byf[j] = *(const f16x8*)(yl + (j * 16 + lr) * 64 + quad * 16);
    asm volatile("s_waitcnt lgkmcnt(0)" ::: "memory");
    __builtin_amdgcn_sched_barrier(0);
    // yl fully consumed into regs -> async prefetch next Y-slab into it
    if (hasNext) {
      const u16* Yn = Yg + (size_t)n * NcY + (bp + 4) * 2048;
#pragma unroll
      for (int c = 0; c < 4; ++c)
        gld_lds16(Yn + c * 512 + (size_t)l * 8, yl + c * 1024);
    }
    // h2 = relu(Y@w2 + b2): D[h = i*16+quad*4+r][t = j*16+lr] -> row t+1
#pragma unroll
    for (int i = 0; i < 4; ++i) {
      const int un = ((i * 2 + (quad >> 1)) ^ lx7p) << 4;
#pragma unroll
      for (int j = 0; j < 4; ++j) {
        f32x4 p = __builtin_amdgcn_mfma_f32_16x16x32_f16(wf[i], byf[j], zz, 0, 0, 0);
        const float v0 = fmaxf(p[0] + b2v[i][0], 0.f);
        const float v1 = fmaxf(p[1] + b2v[i][1], 0.f);
        const float v2 = fmaxf(p[2] + b2v[i][2], 0.f);
        const float v3 = fmaxf(p[3] + b2v[i][3], 0.f);
        uint2 st;
        st.x = pk2h(v0, v1);
        st.y = pk2h(v2, v3);
        *(uint2*)(myl + (j * 16 + lr + 1) * 128 + un + ((quad & 1) << 3)) = st;
      }
    }
    asm volatile("s_waitcnt lgkmcnt(0)" ::: "memory");
    __builtin_amdgcn_sched_barrier(0);
    // TCN phase: reads wlds (W) + myl rows (t+kk) directly (halo-safe)
    f32x4 acc[4][4];
#pragma unroll
    for (int i = 0; i < 4; ++i)
#pragma unroll
      for (int j = 0; j < 4; ++j) acc[i][j] = zz;
#pragma unroll
    for (int ks = 0; ks < 2; ++ks)
#pragma unroll
      for (int kk = 0; kk < 3; ++kk) {
        const int usw = ((ks * 4 + quad) ^ lx7) << 4;
        const int rx7 = (lr + kk) & 7;  // read-row & 7
        const int rsw = ((ks * 4 + quad) ^ rx7) << 4;
        f16x8 afr[4], bfr[4];
#pragma unroll
        for (int i = 0; i < 4; ++i)
          afr[i] = *(const f16x8*)(wlds + kk * 8192 + (i * 16 + lr) * 128 + usw);
#pragma unroll
        for (int j = 0; j < 4; ++j)
          bfr[j] = *(const f16x8*)(myl + (j * 16 + lr + kk) * 128 + rsw);
#pragma unroll
        for (int i = 0; i < 4; ++i)
#pragma unroll
          for (int j = 0; j < 4; ++j)
            acc[i][j] = __builtin_amdgcn_mfma_f32_16x16x32_f16(afr[i], bfr[j],
                                                               acc[i][j], 0, 0, 0);
      }
    // FC epilogue (pure-register; covers part of the prefetch latency)
    f16x2h pacc;
    pacc[0] = (_Float16)0.f; pacc[1] = (_Float16)0.f;
#pragma unroll
    for (int i = 0; i < 4; ++i)
#pragma unroll
      for (int r = 0; r < 4; ++r) {
        const float v0 = fmaxf(acc[i][0][r] + tbv[i][r], 0.f);
        const float v1 = fmaxf(acc[i][1][r] + tbv[i][r], 0.f);
        const float v2 = fmaxf(acc[i][2][r] + tbv[i][r], 0.f);
        const float v3 = fmaxf(acc[i][3][r] + tbv[i][r], 0.f);
        pacc = pkh(v0, v1) * fwh[i * 4 + r][0] + pacc;
        pacc = pkh(v2, v3) * fwh[i * 4 + r][1] + pacc;
      }
    float s = (float)pacc[0] + (float)pacc[1];
#pragma unroll
    for (int off = 32; off > 0; off >>= 1) s += __shfl_xor(s, off, 64);
    if (l == 0) outg[(size_t)(b0 + bp) * NN + n] = s + fcb;
    // prefetch must land before next iteration's byf reads
    if (hasNext) {
      asm volatile("s_waitcnt vmcnt(0)" ::: "memory");
      __builtin_amdgcn_sched_barrier(0);
    }
  }
}

// ---------------------------------------------------------------------------
extern "C" void kernel_launch(void* const* d_in, const int* in_sizes, int n_in,
                              void* d_out, int out_size, void* d_ws, size_t ws_size,
                              hipStream_t stream) {
  const float* xg   = (const float*)d_in[0];
  const float* adjg = (const float*)d_in[1];
  const float* w1g  = (const float*)d_in[2];
  const float* b1g  = (const float*)d_in[3];
  const float* w2g  = (const float*)d_in[4];
  const float* b2g  = (const float*)d_in[5];
  const float* twg  = (const float*)d_in[6];
  const float* tbg  = (const float*)d_in[7];
  const float* fwg  = (const float*)d_in[8];
  const float* fbg  = (const float*)d_in[9];
  float* outg = (float*)d_out;

  char* ws = (char*)d_ws;
  float* Sg = (float*)ws;                      // 4,194,304 B
  u16* adjb = (u16*)(ws + 4194304);            //   524,288 B
  u16* w2t  = (u16*)(ws + 4718592);            //     8,192 B (4KB used)
  u16* Wb   = (u16*)(ws + 4726784);            // 12,582,912 B
  const size_t fixedB = 17309696;
  int CB = 32;
  while (CB > 1 && fixedB + (size_t)CB * 2097152ull > ws_size) CB >>= 1;
  u16* Yg = (u16*)(ws + fixedB);               // 512 rows x CB*2048 cols, f16
  u16* xh = Yg;  // xh (2MB) overlaps Yg: dead before first k2y write
  const int Ncol = CB * 2048;

  kcvt_all<<<4096, 256, 0, stream>>>(adjg, adjb, w2g, w2t, xg, xh);
  kcvt_w<<<512, 256, 0, stream>>>(twg, Wb);
  k0h<<<dim3(32, 8), 256, 0, stream>>>(xh, adjb, Sg);
  for (int b0 = 0; b0 < BB; b0 += CB) {
    k2y<<<dim3(4, CB * 16), 256, 0, stream>>>(adjb, Sg, w1g, b1g, Yg, Ncol, b0);
    k3_tcn<<<dim3(NN), 256, 0, stream>>>(Yg, Wb, w2t, b2g, tbg, fwg, fbg, outg,
                                         b0, Ncol, CB);
  }
}